// Round 4
// baseline (305.292 us; speedup 1.0000x reference)
//
#include <hip/hip_runtime.h>

#define BATCH 16
#define CIN   1024
#define HID   256
#define HW    4096

typedef __attribute__((ext_vector_type(8))) short bf16x8;
typedef __attribute__((ext_vector_type(4))) float f32x4;

struct __align__(16) f4  { float v[4]; };
struct __align__(8)  us4 { unsigned short v[4]; };
struct __align__(16) us8 { unsigned short v[8]; };

__device__ __forceinline__ float bf2f(unsigned short u) {
  unsigned int x = ((unsigned int)u) << 16;
  return __builtin_bit_cast(float, x);
}
__device__ __forceinline__ unsigned short f2bf(float f) {
  unsigned int u = __builtin_bit_cast(unsigned int, f);
  u += 0x7fff + ((u >> 16) & 1);            // round-to-nearest-even
  return (unsigned short)(u >> 16);
}

// direct-to-LDS 16B DMA: LDS dest = wave-uniform base + lane*16, global src per-lane
#define GLOAD_LDS16(g, l) \
  __builtin_amdgcn_global_load_lds((const __attribute__((address_space(1))) unsigned int*)(const void*)(g), \
                                   (__attribute__((address_space(3))) unsigned int*)(void*)(l), 16, 0, 0)

#define VMW4() asm volatile("s_waitcnt vmcnt(4)" ::: "memory")
#define VMW0() asm volatile("s_waitcnt vmcnt(0)" ::: "memory")
#define LGW0() asm volatile("s_waitcnt lgkmcnt(0)" ::: "memory")
#define SBAR() do { __builtin_amdgcn_sched_barrier(0); asm volatile("" ::: "memory"); \
                    __builtin_amdgcn_s_barrier(); \
                    asm volatile("" ::: "memory"); __builtin_amdgcn_sched_barrier(0); } while (0)

// Pre-convert fp32 [256][KD] weights into bf16 K-tile images laid out exactly as the
// GEMM's A_sh LDS expects (XOR-swizzle pre-applied) so A staging is pure DMA.
__global__ __launch_bounds__(256)
void prep_kernel(const float* __restrict__ A1, unsigned short* __restrict__ O1,
                 const float* __restrict__ A2, unsigned short* __restrict__ O2)
{
  const int bidx = blockIdx.x;
  const float* A = (bidx < 256) ? A1 : A2;
  unsigned short* O = (bidx < 256) ? O1 : O2;
  const int shift = (bidx < 256) ? 8 : 6;              // k-quads per row: 256 | 64
  const int f = ((bidx < 256) ? bidx : bidx - 256) * 256 + threadIdx.x;
  const int m = f >> shift, kq4 = f & ((1 << shift) - 1);
  const int kt = kq4 >> 4, kq = kq4 & 15;
  f4 v = *(const f4*)(A + (((size_t)m << shift) + kq4) * 4);
  us4 w = { f2bf(v.v[0]), f2bf(v.v[1]), f2bf(v.v[2]), f2bf(v.v[3]) };
  int byte = kt * 32768 + m * 128 + ((((kq >> 1) ^ (m & 7)) << 4) | ((kq & 1) << 3));
  *(us4*)((char*)O + byte) = w;
}

// C[b][m][pix] = sum_k A[m][k]*B[b][k][pix] + bias[m]
// Pipeline: B LDS double-buffered, A single-buffer DMA, raw barriers + counted vmcnt.
template<int KDIM, bool B_BF16, bool DO_CTX, bool DO_BN>
__global__ __launch_bounds__(512, 4)
void gemm_kernel(const unsigned short* __restrict__ Aswz, const void* __restrict__ Bsrc,
                 const float* __restrict__ bias, unsigned short* __restrict__ Cout,
                 float* __restrict__ ctx_sum, float* __restrict__ bn_sums)
{
  constexpr int NT = KDIM / 64;
  __shared__ unsigned short A_sh[256 * 64];      // [m][k] bf16, swizzled (DMA'd linear)
  __shared__ unsigned short B_sh[2][128 * 64];   // [pix][k] bf16, swizzled, double-buffered
  __shared__ float ctx_lds[1024];
  __shared__ float bn_lds[512];

  const int tid  = threadIdx.x;
  const int lane = tid & 63;
  const int wv   = tid >> 6;
  const int wm   = wv >> 1, wn = wv & 1;         // wave grid 4(M) x 2(N), wave tile 64x64
  const int lr   = lane & 15, lg = lane >> 4;

  const int b    = blockIdx.x >> 5;
  const int pix0 = (blockIdx.x & 31) << 7;

  if (DO_CTX) { for (int i = tid; i < 1024; i += 512) ctx_lds[i] = 0.f; }
  if (DO_BN)  { if (tid < 512) bn_lds[tid] = 0.f; }
  if (DO_CTX || DO_BN) __syncthreads();

  f32x4 acc[4][4] = {};
  const int c4 = tid & 15, q = tid >> 4;         // B staging: thread -> 4 k-rows x 4 pixels

  const float*          xb = (const float*)Bsrc;
  const unsigned short* db = (const unsigned short*)Bsrc;
  const size_t bofs = (size_t)b * KDIM * HW + (size_t)(4 * c4) * HW + pix0 + 4 * q;

  f4  rAf[4], rBf[4];
  us4 rAh[4], rBh[4];

  auto LOADB = [&](int t, f4* rf, us4* rh) {
    const size_t o = bofs + (size_t)t * 64 * HW;
    if constexpr (!B_BF16) {
      #pragma unroll
      for (int i = 0; i < 4; ++i) rf[i] = *(const f4*)(xb + o + (size_t)i * HW);
    } else {
      #pragma unroll
      for (int i = 0; i < 4; ++i) rh[i] = *(const us4*)(db + o + (size_t)i * HW);
    }
  };
  auto ISSUEA = [&](int t) {
    const char* s = (const char*)Aswz + t * 32768 + wv * 1024 + lane * 16;
    char* d = (char*)A_sh + wv * 1024;
    GLOAD_LDS16(s,         d);
    GLOAD_LDS16(s +  8192, d +  8192);
    GLOAD_LDS16(s + 16384, d + 16384);
    GLOAD_LDS16(s + 24576, d + 24576);
  };
  auto WRITEB = [&](int sel, int t, f4* rf, us4* rh) {
    if constexpr (!B_BF16) {
      if constexpr (DO_CTX) {   // fused context-pool partial sums
        #pragma unroll
        for (int i = 0; i < 4; ++i) {
          float s = rf[i].v[0] + rf[i].v[1] + rf[i].v[2] + rf[i].v[3];
          s += __shfl_xor(s, 16, 64);
          s += __shfl_xor(s, 32, 64);
          if (lane < 16) atomicAdd(&ctx_lds[t * 64 + 4 * c4 + i], s);
        }
      }
      #pragma unroll
      for (int j = 0; j < 4; ++j) {
        int pix = 4 * q + j;
        us4 w = { f2bf(rf[0].v[j]), f2bf(rf[1].v[j]), f2bf(rf[2].v[j]), f2bf(rf[3].v[j]) };
        *(us4*)((char*)B_sh[sel] + pix * 128 + ((8 * c4) ^ ((pix & 7) << 4))) = w;
      }
    } else {
      #pragma unroll
      for (int j = 0; j < 4; ++j) {
        int pix = 4 * q + j;
        us4 w = { rh[0].v[j], rh[1].v[j], rh[2].v[j], rh[3].v[j] };
        *(us4*)((char*)B_sh[sel] + pix * 128 + ((8 * c4) ^ ((pix & 7) << 4))) = w;
      }
    }
  };
  auto COMPUTE = [&](int sel) {
    #pragma unroll
    for (int kk = 0; kk < 2; ++kk) {
      bf16x8 af[4], bfr[4];
      #pragma unroll
      for (int mi = 0; mi < 4; ++mi) {
        int row = wm * 64 + mi * 16 + lr;
        af[mi] = *(const bf16x8*)((const char*)A_sh + row * 128 + ((((kk << 2) | lg) ^ (row & 7)) << 4));
      }
      #pragma unroll
      for (int ni = 0; ni < 4; ++ni) {
        int pr = wn * 64 + ni * 16 + lr;
        bfr[ni] = *(const bf16x8*)((const char*)B_sh[sel] + pr * 128 + ((((kk << 2) | lg) ^ (pr & 7)) << 4));
      }
      #pragma unroll
      for (int mi = 0; mi < 4; ++mi)
        #pragma unroll
        for (int ni = 0; ni < 4; ++ni)
          acc[mi][ni] = __builtin_amdgcn_mfma_f32_16x16x32_bf16(af[mi], bfr[ni], acc[mi][ni], 0, 0, 0);
    }
  };

  // prologue: FIFO = [BgA(0), A(0), BgB(1)]
  LOADB(0, rAf, rAh);
  ISSUEA(0);
  LOADB(1, rBf, rBh);

  for (int t = 0; t < NT; t += 2) {
    // ---- half 1: tile t, B_sh[0]
    WRITEB(0, t, rAf, rAh);                 // compiler waits exactly for BgA(t)
    if (t + 2 < NT) { LOADB(t + 2, rAf, rAh); VMW4(); }  // retire thru A(t); BgA(t+2) stays
    else            { VMW0(); }
    LGW0();
    SBAR();
    COMPUTE(0);
    SBAR();
    // ---- half 2: tile t+1, B_sh[1]
    ISSUEA(t + 1);                          // A_sh free: everyone passed the barrier
    WRITEB(1, t + 1, rBf, rBh);
    if (t + 3 < NT) { LOADB(t + 3, rBf, rBh); VMW4(); }  // retire thru A(t+1)
    else            { VMW0(); }
    LGW0();
    SBAR();
    COMPUTE(1);
    SBAR();
    if (t + 2 < NT) ISSUEA(t + 2);
  }

  // ---- epilogue: bias, bf16 store, optional BN partial stats
  #pragma unroll
  for (int mi = 0; mi < 4; ++mi) {
    #pragma unroll
    for (int r = 0; r < 4; ++r) {
      int o = wm * 64 + mi * 16 + lg * 4 + r;   // C/D: col=lane&15, row=(lane>>4)*4+reg
      float bo = bias[o];
      #pragma unroll
      for (int ni = 0; ni < 4; ++ni) {
        int pix = pix0 + wn * 64 + ni * 16 + lr;
        float val = acc[mi][ni][r] + bo;
        Cout[((size_t)(b * HID + o)) * HW + pix] = f2bf(val);
        if (DO_BN) {
          float s = val, s2 = val * val;
          #pragma unroll
          for (int msk = 1; msk < 16; msk <<= 1) {
            s  += __shfl_xor(s,  msk, 64);
            s2 += __shfl_xor(s2, msk, 64);
          }
          if (lr == 0) { atomicAdd(&bn_lds[o], s); atomicAdd(&bn_lds[256 + o], s2); }
        }
      }
    }
  }
  if (DO_CTX || DO_BN) __syncthreads();
  if (DO_CTX) {
    for (int e = tid; e < 1024; e += 512)
      atomicAdd(&ctx_sum[(size_t)b * 1024 + e], ctx_lds[e]);
  }
  if (DO_BN) {
    if (tid < 512) atomicAdd(&bn_sums[tid], bn_lds[tid]);
  }
}

// wave-per-output FC layer: out[b][o] = act(scale * dot(in[b][:], w[o][:]) + bias[o])
template<int K, int N, bool RELU>
__global__ __launch_bounds__(256)
void fc_kernel(const float* __restrict__ in, const float* __restrict__ w,
               const float* __restrict__ bias, float* __restrict__ out, float scale)
{
  const int wid  = (blockIdx.x << 2) | (threadIdx.x >> 6);
  const int lane = threadIdx.x & 63;
  const int b = wid / N, o = wid - b * N;
  const float* ip = in + (size_t)b * K;
  const float* wp = w  + (size_t)o * K;
  float p = 0.f;
  #pragma unroll
  for (int k = 0; k < K / 64; ++k) p += ip[lane + k * 64] * wp[lane + k * 64];
  #pragma unroll
  for (int m = 1; m < 64; m <<= 1) p += __shfl_xor(p, m, 64);
  if (lane == 0) {
    float v = p * scale + bias[o];
    out[(size_t)b * N + o] = RELU ? fmaxf(v, 0.f) : v;
  }
}

// per-sample per-group depthwise 3x3, padding=1; LDS-staged plane, us8 vector I/O
__global__ __launch_bounds__(256)
void dwconv_kernel(const unsigned short* __restrict__ xt, const float* __restrict__ kern,
                   unsigned short* __restrict__ dw)
{
  __shared__ unsigned short pl[64 * 72];        // 72-short row pitch (16B-aligned rows)
  __shared__ float kf[9];
  const int b  = blockIdx.x >> 8;
  const int ch = blockIdx.x & 255;
  if (threadIdx.x < 9) kf[threadIdx.x] = kern[b * 72 + (ch >> 5) * 9 + threadIdx.x];
  const unsigned short* xp = xt + ((size_t)(b * HID + ch) << 12);
  unsigned short*       dp = dw + ((size_t)(b * HID + ch) << 12);
  const int r  = threadIdx.x >> 2;              // row 0..63
  const int c0 = (threadIdx.x & 3) << 4;        // col base 0/16/32/48
  *(us8*)&pl[r * 72 + c0]     = *(const us8*)(xp + r * 64 + c0);
  *(us8*)&pl[r * 72 + c0 + 8] = *(const us8*)(xp + r * 64 + c0 + 8);
  __syncthreads();
  float rows[3][18];
  #pragma unroll
  for (int ky = 0; ky < 3; ++ky) {
    int rr = r + ky - 1;
    bool rok = (unsigned)rr < 64u;
    #pragma unroll
    for (int i = 0; i < 18; ++i) {
      int cc = c0 - 1 + i;
      rows[ky][i] = (rok && (unsigned)cc < 64u) ? bf2f(pl[rr * 72 + cc]) : 0.f;
    }
  }
  us8 o0, o1;
  #pragma unroll
  for (int j = 0; j < 16; ++j) {
    float a = 0.f;
    #pragma unroll
    for (int ky = 0; ky < 3; ++ky)
      #pragma unroll
      for (int kx = 0; kx < 3; ++kx)
        a += rows[ky][j + kx] * kf[ky * 3 + kx];
    if (j < 8) o0.v[j] = f2bf(a); else o1.v[j - 8] = f2bf(a);
  }
  *(us8*)(dp + r * 64 + c0)     = o0;
  *(us8*)(dp + r * 64 + c0 + 8) = o1;
}

__global__ void bn_finalize_kernel(const float* __restrict__ bn_sums,
                                   const float* __restrict__ gamma, const float* __restrict__ beta,
                                   float* __restrict__ scale, float* __restrict__ shift)
{
  int t = threadIdx.x;
  if (t < 256) {
    const float inv_n = 1.f / 65536.f;          // B*H*W
    float m  = bn_sums[t] * inv_n;
    float v  = bn_sums[256 + t] * inv_n - m * m;
    float sc = gamma[t] * rsqrtf(v + 1e-5f);
    scale[t] = sc;
    shift[t] = beta[t] - m * sc;
  }
}

// out = xt + scale[o]*out_trans + shift[o]   (fp32 store)
__global__ __launch_bounds__(256)
void final_kernel(const unsigned short* __restrict__ xt, const unsigned short* __restrict__ ot,
                  const float* __restrict__ scale, const float* __restrict__ shift,
                  float* __restrict__ out)
{
  int g = blockIdx.x * 256 + threadIdx.x;       // group of 4 elements
  const int stride = 4096 * 256;
  #pragma unroll
  for (int it = 0; it < 4; ++it, g += stride) {
    int o = (g >> 10) & 255;
    us4 a = ((const us4*)xt)[g];
    us4 c = ((const us4*)ot)[g];
    float s = scale[o], h = shift[o];
    f4 r;
    #pragma unroll
    for (int j = 0; j < 4; ++j) r.v[j] = bf2f(a.v[j]) + s * bf2f(c.v[j]) + h;
    *(f4*)(out + (size_t)g * 4) = r;
  }
}

extern "C" void kernel_launch(void* const* d_in, const int* in_sizes, int n_in,
                              void* d_out, int out_size, void* d_ws, size_t ws_size,
                              hipStream_t stream)
{
  const float* x     = (const float*)d_in[0];
  const float* ctx_w = (const float*)d_in[1];
  const float* ctx_b = (const float*)d_in[2];
  const float* kg_w1 = (const float*)d_in[3];
  const float* kg_b1 = (const float*)d_in[4];
  const float* kg_w2 = (const float*)d_in[5];
  const float* kg_b2 = (const float*)d_in[6];
  const float* in_w  = (const float*)d_in[7];
  const float* in_b  = (const float*)d_in[8];
  const float* out_w = (const float*)d_in[9];
  const float* out_b = (const float*)d_in[10];
  const float* gamma = (const float*)d_in[11];
  const float* beta  = (const float*)d_in[12];
  float* out = (float*)d_out;

  char* ws = (char*)d_ws;
  unsigned short* xt  = (unsigned short*)ws;                 // 32 MiB bf16 xt
  unsigned short* dwb = (unsigned short*)(ws + 33554432);    // 32 MiB bf16 dw / out_trans
  float* ctx_sum = (float*)(ws + 67108864);                  // [16][1024]
  float* bn_sums = ctx_sum + 16384;                          // [512]
  float* kern    = bn_sums + 512;                            // [16][72]
  float* scale   = kern + 1152;                              // [256]
  float* shift   = scale + 256;                              // [256]
  float* ctxbuf  = shift + 256;                              // [16][256]
  float* hddnbuf = ctxbuf + 4096;                            // [16][512]
  unsigned short* aswz1 = (unsigned short*)(ws + 67108864 + 131072);            // 512 KiB
  unsigned short* aswz2 = (unsigned short*)(ws + 67108864 + 131072 + 524288);   // 128 KiB

  hipMemsetAsync(ctx_sum, 0, (16384 + 512) * sizeof(float), stream);

  prep_kernel<<<320, 256, 0, stream>>>(in_w, aswz1, out_w, aswz2);
  gemm_kernel<1024, false, true,  false><<<512, 512, 0, stream>>>(aswz1, x,   in_b,  xt,  ctx_sum, nullptr);
  fc_kernel<1024, 256, true ><<<1024, 256, 0, stream>>>(ctx_sum, ctx_w, ctx_b, ctxbuf, 1.f / 4096.f);
  fc_kernel< 256, 512, true ><<<2048, 256, 0, stream>>>(ctxbuf,  kg_w1, kg_b1, hddnbuf, 1.f);
  fc_kernel< 512,  72, false><<< 288, 256, 0, stream>>>(hddnbuf, kg_w2, kg_b2, kern,    1.f);
  dwconv_kernel<<<4096, 256, 0, stream>>>(xt, kern, dwb);
  gemm_kernel<256,  true,  false, true ><<<512, 512, 0, stream>>>(aswz2, dwb, out_b, dwb, nullptr, bn_sums);
  bn_finalize_kernel<<<1, 256, 0, stream>>>(bn_sums, gamma, beta, scale, shift);
  final_kernel<<<4096, 256, 0, stream>>>(xt, dwb, scale, shift, out);
}

// Round 5
// 227.276 us; speedup vs baseline: 1.3433x; 1.3433x over previous
//
#include <hip/hip_runtime.h>

#define BATCH 16
#define CIN   1024
#define HID   256
#define HW    4096

typedef __attribute__((ext_vector_type(8))) short bf16x8;
typedef __attribute__((ext_vector_type(4))) float f32x4;

struct __align__(16) f4  { float v[4]; };
struct __align__(8)  us4 { unsigned short v[4]; };
struct __align__(16) us8 { unsigned short v[8]; };

__device__ __forceinline__ float bf2f(unsigned short u) {
  unsigned int x = ((unsigned int)u) << 16;
  return __builtin_bit_cast(float, x);
}
__device__ __forceinline__ unsigned short f2bf(float f) {
  unsigned int u = __builtin_bit_cast(unsigned int, f);
  u += 0x7fff + ((u >> 16) & 1);            // round-to-nearest-even
  return (unsigned short)(u >> 16);
}

// lgkm-only barrier: drain ds_writes, leave ALL vmem (B/A prefetch) in flight
#define LGWB() do { __builtin_amdgcn_sched_barrier(0); \
  asm volatile("s_waitcnt lgkmcnt(0)" ::: "memory"); \
  __builtin_amdgcn_s_barrier(); \
  __builtin_amdgcn_sched_barrier(0); } while (0)

// Pre-convert fp32 [256][KD] weights into per-lane bf16 MFMA A-fragments:
// unit u -> [tile][wm][kk][mi][lane], 16 B each; in-kernel: wave reads its 8 frags
// as global_load_dwordx4 at base + {0..7}*1024, no LDS, no transpose.
__global__ __launch_bounds__(256)
void prep_kernel(const float* __restrict__ A1, unsigned short* __restrict__ O1,
                 const float* __restrict__ A2, unsigned short* __restrict__ O2)
{
  const int bidx = blockIdx.x;
  const float* A; unsigned short* O; int KD, u;
  if (bidx < 128) { A = A1; O = O1; KD = 1024; u = bidx * 256 + threadIdx.x; }
  else            { A = A2; O = O2; KD = 256;  u = (bidx - 128) * 256 + threadIdx.x; }
  const int t    = u >> 11;                 // K-tile (2048 units of 16 B per tile)
  const int r    = u & 2047;
  const int wm   = r >> 9, kk = (r >> 8) & 1, mi = (r >> 6) & 3, lane = r & 63;
  const int row  = wm * 64 + mi * 16 + (lane & 15);
  const int k    = t * 64 + kk * 32 + (lane >> 4) * 8;
  f4 v0 = *(const f4*)(A + (size_t)row * KD + k);
  f4 v1 = *(const f4*)(A + (size_t)row * KD + k + 4);
  us8 w = { f2bf(v0.v[0]), f2bf(v0.v[1]), f2bf(v0.v[2]), f2bf(v0.v[3]),
            f2bf(v1.v[0]), f2bf(v1.v[1]), f2bf(v1.v[2]), f2bf(v1.v[3]) };
  *(us8*)(O + (size_t)u * 8) = w;
}

// C[b][m][pix] = sum_k A[m][k]*B[b][k][pix] + bias[m]
// A: register double-buffer from fragment stream (L2). B: LDS double-buffer,
// reg-prefetch depth 2. One lgkm-only barrier per K-tile; vmem never drains.
template<int KDIM, bool B_BF16, bool DO_CTX, bool DO_BN>
__global__ __launch_bounds__(512, 2)
void gemm_kernel(const unsigned short* __restrict__ Afrag, const void* __restrict__ Bsrc,
                 const float* __restrict__ bias, unsigned short* __restrict__ Cout,
                 float* __restrict__ ctx_sum, float* __restrict__ bn_sums)
{
  constexpr int NT = KDIM / 64;
  __shared__ unsigned short B_sh[2][128 * 64];   // [pix][k] bf16, XOR-swizzled
  __shared__ float ctx_lds[1024];
  __shared__ float bn_lds[512];

  const int tid  = threadIdx.x;
  const int lane = tid & 63;
  const int wv   = tid >> 6;
  const int wm   = wv >> 1, wn = wv & 1;         // wave grid 4(M) x 2(N), tile 64x64
  const int lr   = lane & 15, lg = lane >> 4;

  const int b    = blockIdx.x >> 5;
  const int pix0 = (blockIdx.x & 31) << 7;

  if (DO_CTX) { for (int i = tid; i < 1024; i += 512) ctx_lds[i] = 0.f; }
  if (DO_BN)  { if (tid < 512) bn_lds[tid] = 0.f; }
  if (DO_CTX || DO_BN) __syncthreads();

  f32x4 acc[4][4] = {};
  const int c4 = tid & 15, q = tid >> 4;         // B staging: 4 k-rows x 4 pixels

  const float*          xb = (const float*)Bsrc;
  const unsigned short* db = (const unsigned short*)Bsrc;
  const size_t bofs = (size_t)b * KDIM * HW + (size_t)(4 * c4) * HW + pix0 + 4 * q;
  const char* abase = (const char*)Afrag + wm * 8192 + lane * 16;

  bf16x8 aA[8], aB[8];                           // A frag double-buffer (regs)
  f4  rfA[4], rfB[4];                            // B prefetch sets (fp32 path)
  us4 rhA[4], rhB[4];                            // B prefetch sets (bf16 path)

  auto ISSUE_A = [&](int t, bf16x8* a) {
    const char* p = abase + t * 32768;
    #pragma unroll
    for (int i = 0; i < 8; ++i) a[i] = *(const bf16x8*)(p + i * 1024);
  };
  auto LOADB = [&](int t, f4* rf, us4* rh) {
    const size_t o = bofs + (size_t)t * 64 * HW;
    if constexpr (!B_BF16) {
      #pragma unroll
      for (int i = 0; i < 4; ++i) rf[i] = *(const f4*)(xb + o + (size_t)i * HW);
    } else {
      #pragma unroll
      for (int i = 0; i < 4; ++i) rh[i] = *(const us4*)(db + o + (size_t)i * HW);
    }
  };
  auto WRITEB = [&](int sel, int t, f4* rf, us4* rh) {
    if constexpr (!B_BF16) {
      if constexpr (DO_CTX) {   // fused context-pool partial sums
        #pragma unroll
        for (int i = 0; i < 4; ++i) {
          float s = rf[i].v[0] + rf[i].v[1] + rf[i].v[2] + rf[i].v[3];
          s += __shfl_xor(s, 16, 64);
          s += __shfl_xor(s, 32, 64);
          if (lane < 16) atomicAdd(&ctx_lds[t * 64 + 4 * c4 + i], s);
        }
      }
      #pragma unroll
      for (int j = 0; j < 4; ++j) {
        int pix = 4 * q + j;
        us4 w = { f2bf(rf[0].v[j]), f2bf(rf[1].v[j]), f2bf(rf[2].v[j]), f2bf(rf[3].v[j]) };
        *(us4*)((char*)B_sh[sel] + pix * 128 + ((8 * c4) ^ ((pix & 7) << 4))) = w;
      }
    } else {
      #pragma unroll
      for (int j = 0; j < 4; ++j) {
        int pix = 4 * q + j;
        us4 w = { rh[0].v[j], rh[1].v[j], rh[2].v[j], rh[3].v[j] };
        *(us4*)((char*)B_sh[sel] + pix * 128 + ((8 * c4) ^ ((pix & 7) << 4))) = w;
      }
    }
  };
  auto COMPUTE = [&](int sel, bf16x8* a) {
    #pragma unroll
    for (int kk = 0; kk < 2; ++kk) {
      bf16x8 bfr[4];
      #pragma unroll
      for (int ni = 0; ni < 4; ++ni) {
        int pr = wn * 64 + ni * 16 + lr;
        bfr[ni] = *(const bf16x8*)((const char*)B_sh[sel] + pr * 128 + ((((kk << 2) | lg) ^ (pr & 7)) << 4));
      }
      #pragma unroll
      for (int mi = 0; mi < 4; ++mi)
        #pragma unroll
        for (int ni = 0; ni < 4; ++ni)
          acc[mi][ni] = __builtin_amdgcn_mfma_f32_16x16x32_bf16(a[kk * 4 + mi], bfr[ni], acc[mi][ni], 0, 0, 0);
    }
  };

  // prologue: A(0) + B(0),B(1) in flight
  ISSUE_A(0, aA);
  LOADB(0, rfA, rhA);
  LOADB(1, rfB, rhB);

  #pragma unroll
  for (int t = 0; t < NT; t += 2) {
    // ---- even tile t: B set A -> B_sh[0], compute with aA
    WRITEB(0, t, rfA, rhA);
    if (t + 2 < NT) LOADB(t + 2, rfA, rhA);
    ISSUE_A(t + 1, aB);
    LGWB();
    COMPUTE(0, aA);
    // ---- odd tile t+1: B set B -> B_sh[1], compute with aB
    WRITEB(1, t + 1, rfB, rhB);
    if (t + 3 < NT) LOADB(t + 3, rfB, rhB);
    if (t + 2 < NT) ISSUE_A(t + 2, aA);
    LGWB();
    COMPUTE(1, aB);
  }

  // ---- epilogue: bias, bf16 store, optional BN partial stats
  #pragma unroll
  for (int mi = 0; mi < 4; ++mi) {
    #pragma unroll
    for (int r = 0; r < 4; ++r) {
      int o = wm * 64 + mi * 16 + lg * 4 + r;   // C/D: col=lane&15, row=(lane>>4)*4+reg
      float bo = bias[o];
      #pragma unroll
      for (int ni = 0; ni < 4; ++ni) {
        int pix = pix0 + wn * 64 + ni * 16 + lr;
        float val = acc[mi][ni][r] + bo;
        Cout[((size_t)(b * HID + o)) * HW + pix] = f2bf(val);
        if (DO_BN) {
          float s = val, s2 = val * val;
          #pragma unroll
          for (int msk = 1; msk < 16; msk <<= 1) {
            s  += __shfl_xor(s,  msk, 64);
            s2 += __shfl_xor(s2, msk, 64);
          }
          if (lr == 0) { atomicAdd(&bn_lds[o], s); atomicAdd(&bn_lds[256 + o], s2); }
        }
      }
    }
  }
  if (DO_CTX || DO_BN) __syncthreads();
  if (DO_CTX) {
    for (int e = tid; e < 1024; e += 512)
      atomicAdd(&ctx_sum[(size_t)b * 1024 + e], ctx_lds[e]);
  }
  if (DO_BN) {
    if (tid < 512) atomicAdd(&bn_sums[tid], bn_lds[tid]);
  }
}

// wave-per-output FC layer: out[b][o] = act(scale * dot(in[b][:], w[o][:]) + bias[o])
template<int K, int N, bool RELU>
__global__ __launch_bounds__(256)
void fc_kernel(const float* __restrict__ in, const float* __restrict__ w,
               const float* __restrict__ bias, float* __restrict__ out, float scale)
{
  const int wid  = (blockIdx.x << 2) | (threadIdx.x >> 6);
  const int lane = threadIdx.x & 63;
  const int b = wid / N, o = wid - b * N;
  const float* ip = in + (size_t)b * K;
  const float* wp = w  + (size_t)o * K;
  float p = 0.f;
  #pragma unroll
  for (int k = 0; k < K / 64; ++k) p += ip[lane + k * 64] * wp[lane + k * 64];
  #pragma unroll
  for (int m = 1; m < 64; m <<= 1) p += __shfl_xor(p, m, 64);
  if (lane == 0) {
    float v = p * scale + bias[o];
    out[(size_t)b * N + o] = RELU ? fmaxf(v, 0.f) : v;
  }
}

// per-sample per-group depthwise 3x3, padding=1; LDS-staged plane, us8 vector I/O
__global__ __launch_bounds__(256)
void dwconv_kernel(const unsigned short* __restrict__ xt, const float* __restrict__ kern,
                   unsigned short* __restrict__ dw)
{
  __shared__ unsigned short pl[64 * 72];        // 72-short row pitch (16B-aligned rows)
  __shared__ float kf[9];
  const int b  = blockIdx.x >> 8;
  const int ch = blockIdx.x & 255;
  if (threadIdx.x < 9) kf[threadIdx.x] = kern[b * 72 + (ch >> 5) * 9 + threadIdx.x];
  const unsigned short* xp = xt + ((size_t)(b * HID + ch) << 12);
  unsigned short*       dp = dw + ((size_t)(b * HID + ch) << 12);
  const int r  = threadIdx.x >> 2;              // row 0..63
  const int c0 = (threadIdx.x & 3) << 4;        // col base 0/16/32/48
  *(us8*)&pl[r * 72 + c0]     = *(const us8*)(xp + r * 64 + c0);
  *(us8*)&pl[r * 72 + c0 + 8] = *(const us8*)(xp + r * 64 + c0 + 8);
  __syncthreads();
  float rows[3][18];
  #pragma unroll
  for (int ky = 0; ky < 3; ++ky) {
    int rr = r + ky - 1;
    bool rok = (unsigned)rr < 64u;
    #pragma unroll
    for (int i = 0; i < 18; ++i) {
      int cc = c0 - 1 + i;
      rows[ky][i] = (rok && (unsigned)cc < 64u) ? bf2f(pl[rr * 72 + cc]) : 0.f;
    }
  }
  us8 o0, o1;
  #pragma unroll
  for (int j = 0; j < 16; ++j) {
    float a = 0.f;
    #pragma unroll
    for (int ky = 0; ky < 3; ++ky)
      #pragma unroll
      for (int kx = 0; kx < 3; ++kx)
        a += rows[ky][j + kx] * kf[ky * 3 + kx];
    if (j < 8) o0.v[j] = f2bf(a); else o1.v[j - 8] = f2bf(a);
  }
  *(us8*)(dp + r * 64 + c0)     = o0;
  *(us8*)(dp + r * 64 + c0 + 8) = o1;
}

__global__ void bn_finalize_kernel(const float* __restrict__ bn_sums,
                                   const float* __restrict__ gamma, const float* __restrict__ beta,
                                   float* __restrict__ scale, float* __restrict__ shift)
{
  int t = threadIdx.x;
  if (t < 256) {
    const float inv_n = 1.f / 65536.f;          // B*H*W
    float m  = bn_sums[t] * inv_n;
    float v  = bn_sums[256 + t] * inv_n - m * m;
    float sc = gamma[t] * rsqrtf(v + 1e-5f);
    scale[t] = sc;
    shift[t] = beta[t] - m * sc;
  }
}

// out = xt + scale[o]*out_trans + shift[o]   (fp32 store)
__global__ __launch_bounds__(256)
void final_kernel(const unsigned short* __restrict__ xt, const unsigned short* __restrict__ ot,
                  const float* __restrict__ scale, const float* __restrict__ shift,
                  float* __restrict__ out)
{
  int g = blockIdx.x * 256 + threadIdx.x;       // group of 4 elements
  const int stride = 4096 * 256;
  #pragma unroll
  for (int it = 0; it < 4; ++it, g += stride) {
    int o = (g >> 10) & 255;
    us4 a = ((const us4*)xt)[g];
    us4 c = ((const us4*)ot)[g];
    float s = scale[o], h = shift[o];
    f4 r;
    #pragma unroll
    for (int j = 0; j < 4; ++j) r.v[j] = bf2f(a.v[j]) + s * bf2f(c.v[j]) + h;
    *(f4*)(out + (size_t)g * 4) = r;
  }
}

extern "C" void kernel_launch(void* const* d_in, const int* in_sizes, int n_in,
                              void* d_out, int out_size, void* d_ws, size_t ws_size,
                              hipStream_t stream)
{
  const float* x     = (const float*)d_in[0];
  const float* ctx_w = (const float*)d_in[1];
  const float* ctx_b = (const float*)d_in[2];
  const float* kg_w1 = (const float*)d_in[3];
  const float* kg_b1 = (const float*)d_in[4];
  const float* kg_w2 = (const float*)d_in[5];
  const float* kg_b2 = (const float*)d_in[6];
  const float* in_w  = (const float*)d_in[7];
  const float* in_b  = (const float*)d_in[8];
  const float* out_w = (const float*)d_in[9];
  const float* out_b = (const float*)d_in[10];
  const float* gamma = (const float*)d_in[11];
  const float* beta  = (const float*)d_in[12];
  float* out = (float*)d_out;

  char* ws = (char*)d_ws;
  unsigned short* xt  = (unsigned short*)ws;                 // 32 MiB bf16 xt
  unsigned short* dwb = (unsigned short*)(ws + 33554432);    // 32 MiB bf16 dw / out_trans
  float* ctx_sum = (float*)(ws + 67108864);                  // [16][1024]
  float* bn_sums = ctx_sum + 16384;                          // [512]
  float* kern    = bn_sums + 512;                            // [16][72]
  float* scale   = kern + 1152;                              // [256]
  float* shift   = scale + 256;                              // [256]
  float* ctxbuf  = shift + 256;                              // [16][256]
  float* hddnbuf = ctxbuf + 4096;                            // [16][512]
  unsigned short* afrag1 = (unsigned short*)(ws + 67108864 + 131072);            // 512 KiB
  unsigned short* afrag2 = (unsigned short*)(ws + 67108864 + 131072 + 524288);   // 128 KiB

  hipMemsetAsync(ctx_sum, 0, (16384 + 512) * sizeof(float), stream);

  prep_kernel<<<160, 256, 0, stream>>>(in_w, afrag1, out_w, afrag2);
  gemm_kernel<1024, false, true,  false><<<512, 512, 0, stream>>>(afrag1, x,   in_b,  xt,  ctx_sum, nullptr);
  fc_kernel<1024, 256, true ><<<1024, 256, 0, stream>>>(ctx_sum, ctx_w, ctx_b, ctxbuf, 1.f / 4096.f);
  fc_kernel< 256, 512, true ><<<2048, 256, 0, stream>>>(ctxbuf,  kg_w1, kg_b1, hddnbuf, 1.f);
  fc_kernel< 512,  72, false><<< 288, 256, 0, stream>>>(hddnbuf, kg_w2, kg_b2, kern,    1.f);
  dwconv_kernel<<<4096, 256, 0, stream>>>(xt, kern, dwb);
  gemm_kernel<256,  true,  false, true ><<<512, 512, 0, stream>>>(afrag2, dwb, out_b, dwb, nullptr, bn_sums);
  bn_finalize_kernel<<<1, 256, 0, stream>>>(bn_sums, gamma, beta, scale, shift);
  final_kernel<<<4096, 256, 0, stream>>>(xt, dwb, scale, shift, out);
}

// Round 6
// 212.549 us; speedup vs baseline: 1.4363x; 1.0693x over previous
//
#include <hip/hip_runtime.h>

#define BATCH 16
#define CIN   1024
#define HID   256
#define HW    4096

typedef __attribute__((ext_vector_type(8))) short bf16x8;
typedef __attribute__((ext_vector_type(4))) float f32x4;

struct __align__(16) f4  { float v[4]; };
struct __align__(8)  us4 { unsigned short v[4]; };
struct __align__(16) us8 { unsigned short v[8]; };

__device__ __forceinline__ float bf2f(unsigned short u) {
  unsigned int x = ((unsigned int)u) << 16;
  return __builtin_bit_cast(float, x);
}
__device__ __forceinline__ unsigned short f2bf(float f) {
  unsigned int u = __builtin_bit_cast(unsigned int, f);
  u += 0x7fff + ((u >> 16) & 1);            // round-to-nearest-even
  return (unsigned short)(u >> 16);
}

// lgkm-only barrier: drain ds_writes, leave ALL vmem (B/A prefetch) in flight
#define LGWB() do { __builtin_amdgcn_sched_barrier(0); \
  asm volatile("s_waitcnt lgkmcnt(0)" ::: "memory"); \
  __builtin_amdgcn_s_barrier(); \
  __builtin_amdgcn_sched_barrier(0); } while (0)

// Pre-convert fp32 [256][KD] weights into per-lane bf16 MFMA A-fragments:
// unit u -> [tile][wm][kk][mi][lane], 16 B each. Trailing blocks zero ctx/bn sums.
__global__ __launch_bounds__(256)
void prep_kernel(const float* __restrict__ A1, unsigned short* __restrict__ O1,
                 const float* __restrict__ A2, unsigned short* __restrict__ O2,
                 float* __restrict__ zbuf)
{
  const int bidx = blockIdx.x;
  if (bidx >= 160) {                        // zero ctx_sum[16384] + bn_sums[512]
    int idx = (bidx - 160) * 256 + threadIdx.x;
    if (idx < 16896) zbuf[idx] = 0.f;
    return;
  }
  const float* A; unsigned short* O; int KD, u;
  if (bidx < 128) { A = A1; O = O1; KD = 1024; u = bidx * 256 + threadIdx.x; }
  else            { A = A2; O = O2; KD = 256;  u = (bidx - 128) * 256 + threadIdx.x; }
  const int t    = u >> 11;                 // K-tile (2048 units of 16 B per tile)
  const int r    = u & 2047;
  const int wm   = r >> 9, kk = (r >> 8) & 1, mi = (r >> 6) & 3, lane = r & 63;
  const int row  = wm * 64 + mi * 16 + (lane & 15);
  const int k    = t * 64 + kk * 32 + (lane >> 4) * 8;
  f4 v0 = *(const f4*)(A + (size_t)row * KD + k);
  f4 v1 = *(const f4*)(A + (size_t)row * KD + k + 4);
  us8 w = { f2bf(v0.v[0]), f2bf(v0.v[1]), f2bf(v0.v[2]), f2bf(v0.v[3]),
            f2bf(v1.v[0]), f2bf(v1.v[1]), f2bf(v1.v[2]), f2bf(v1.v[3]) };
  *(us8*)(O + (size_t)u * 8) = w;
}

// ============ GEMM1: C[b][m][pix] = sum_k A[m][k]*x[b][k][pix] + bias[m] =========
// A: register double-buffer from fragment stream (L2). B: LDS double-buffer,
// reg-prefetch depth 2. One lgkm-only barrier per K-tile; vmem never drains.
template<int KDIM, bool B_BF16, bool DO_CTX, bool DO_BN>
__global__ __launch_bounds__(512, 2)
void gemm_kernel(const unsigned short* __restrict__ Afrag, const void* __restrict__ Bsrc,
                 const float* __restrict__ bias, unsigned short* __restrict__ Cout,
                 float* __restrict__ ctx_sum, float* __restrict__ bn_sums)
{
  constexpr int NT = KDIM / 64;
  __shared__ unsigned short B_sh[2][128 * 64];   // [pix][k] bf16, XOR-swizzled
  __shared__ float ctx_lds[1024];
  __shared__ float bn_lds[512];

  const int tid  = threadIdx.x;
  const int lane = tid & 63;
  const int wv   = tid >> 6;
  const int wm   = wv >> 1, wn = wv & 1;         // wave grid 4(M) x 2(N), tile 64x64
  const int lr   = lane & 15, lg = lane >> 4;

  const int b    = blockIdx.x >> 5;
  const int pix0 = (blockIdx.x & 31) << 7;

  if (DO_CTX) { for (int i = tid; i < 1024; i += 512) ctx_lds[i] = 0.f; }
  if (DO_BN)  { if (tid < 512) bn_lds[tid] = 0.f; }
  if (DO_CTX || DO_BN) __syncthreads();

  f32x4 acc[4][4] = {};
  const int c4 = tid & 15, q = tid >> 4;         // B staging: 4 k-rows x 4 pixels

  const float*          xb = (const float*)Bsrc;
  const unsigned short* db = (const unsigned short*)Bsrc;
  const size_t bofs = (size_t)b * KDIM * HW + (size_t)(4 * c4) * HW + pix0 + 4 * q;
  const char* abase = (const char*)Afrag + wm * 8192 + lane * 16;

  bf16x8 aA[8], aB[8];                           // A frag double-buffer (regs)
  f4  rfA[4], rfB[4];                            // B prefetch sets (fp32 path)
  us4 rhA[4], rhB[4];                            // B prefetch sets (bf16 path)

  auto ISSUE_A = [&](int t, bf16x8* a) {
    const char* p = abase + t * 32768;
    #pragma unroll
    for (int i = 0; i < 8; ++i) a[i] = *(const bf16x8*)(p + i * 1024);
  };
  auto LOADB = [&](int t, f4* rf, us4* rh) {
    const size_t o = bofs + (size_t)t * 64 * HW;
    if constexpr (!B_BF16) {
      #pragma unroll
      for (int i = 0; i < 4; ++i) rf[i] = *(const f4*)(xb + o + (size_t)i * HW);
    } else {
      #pragma unroll
      for (int i = 0; i < 4; ++i) rh[i] = *(const us4*)(db + o + (size_t)i * HW);
    }
  };
  auto WRITEB = [&](int sel, int t, f4* rf, us4* rh) {
    if constexpr (!B_BF16) {
      if constexpr (DO_CTX) {   // fused context-pool partial sums
        #pragma unroll
        for (int i = 0; i < 4; ++i) {
          float s = rf[i].v[0] + rf[i].v[1] + rf[i].v[2] + rf[i].v[3];
          s += __shfl_xor(s, 16, 64);
          s += __shfl_xor(s, 32, 64);
          if (lane < 16) atomicAdd(&ctx_lds[t * 64 + 4 * c4 + i], s);
        }
      }
      #pragma unroll
      for (int j = 0; j < 4; ++j) {
        int pix = 4 * q + j;
        us4 w = { f2bf(rf[0].v[j]), f2bf(rf[1].v[j]), f2bf(rf[2].v[j]), f2bf(rf[3].v[j]) };
        *(us4*)((char*)B_sh[sel] + pix * 128 + ((8 * c4) ^ ((pix & 7) << 4))) = w;
      }
    } else {
      #pragma unroll
      for (int j = 0; j < 4; ++j) {
        int pix = 4 * q + j;
        us4 w = { rh[0].v[j], rh[1].v[j], rh[2].v[j], rh[3].v[j] };
        *(us4*)((char*)B_sh[sel] + pix * 128 + ((8 * c4) ^ ((pix & 7) << 4))) = w;
      }
    }
  };
  auto COMPUTE = [&](int sel, bf16x8* a) {
    #pragma unroll
    for (int kk = 0; kk < 2; ++kk) {
      bf16x8 bfr[4];
      #pragma unroll
      for (int ni = 0; ni < 4; ++ni) {
        int pr = wn * 64 + ni * 16 + lr;
        bfr[ni] = *(const bf16x8*)((const char*)B_sh[sel] + pr * 128 + ((((kk << 2) | lg) ^ (pr & 7)) << 4));
      }
      #pragma unroll
      for (int mi = 0; mi < 4; ++mi)
        #pragma unroll
        for (int ni = 0; ni < 4; ++ni)
          acc[mi][ni] = __builtin_amdgcn_mfma_f32_16x16x32_bf16(a[kk * 4 + mi], bfr[ni], acc[mi][ni], 0, 0, 0);
    }
  };

  // prologue: A(0) + B(0),B(1) in flight
  ISSUE_A(0, aA);
  LOADB(0, rfA, rhA);
  LOADB(1, rfB, rhB);

  #pragma unroll
  for (int t = 0; t < NT; t += 2) {
    WRITEB(0, t, rfA, rhA);
    if (t + 2 < NT) LOADB(t + 2, rfA, rhA);
    ISSUE_A(t + 1, aB);
    LGWB();
    COMPUTE(0, aA);
    WRITEB(1, t + 1, rfB, rhB);
    if (t + 3 < NT) LOADB(t + 3, rfB, rhB);
    if (t + 2 < NT) ISSUE_A(t + 2, aA);
    LGWB();
    COMPUTE(1, aB);
  }

  // ---- epilogue: bias, bf16 store, optional BN partial stats
  #pragma unroll
  for (int mi = 0; mi < 4; ++mi) {
    #pragma unroll
    for (int r = 0; r < 4; ++r) {
      int o = wm * 64 + mi * 16 + lg * 4 + r;   // C/D: col=lane&15, row=(lane>>4)*4+reg
      float bo = bias[o];
      #pragma unroll
      for (int ni = 0; ni < 4; ++ni) {
        int pix = pix0 + wn * 64 + ni * 16 + lr;
        float val = acc[mi][ni][r] + bo;
        Cout[((size_t)(b * HID + o)) * HW + pix] = f2bf(val);
        if (DO_BN) {
          float s = val, s2 = val * val;
          #pragma unroll
          for (int msk = 1; msk < 16; msk <<= 1) {
            s  += __shfl_xor(s,  msk, 64);
            s2 += __shfl_xor(s2, msk, 64);
          }
          if (lr == 0) { atomicAdd(&bn_lds[o], s); atomicAdd(&bn_lds[256 + o], s2); }
        }
      }
    }
  }
  if (DO_CTX || DO_BN) __syncthreads();
  if (DO_CTX) {
    for (int e = tid; e < 1024; e += 512)
      atomicAdd(&ctx_sum[(size_t)b * 1024 + e], ctx_lds[e]);
  }
  if (DO_BN) {
    if (tid < 512) atomicAdd(&bn_sums[tid], bn_lds[tid]);
  }
}

// ============ GEMM2 fused with depthwise conv ============
// out_trans[b][o][pix] = sum_ch out_w[o][ch] * dw[b][ch][pix] + out_b[o]
// dw computed on the fly from xt (LDS slab: 64 ch x 4 rows x 64 cols per k-tile).
__global__ __launch_bounds__(512, 2)
void gemm2_fused_kernel(const unsigned short* __restrict__ Afrag,
                        const unsigned short* __restrict__ xt,
                        const float* __restrict__ kern, const float* __restrict__ bias,
                        unsigned short* __restrict__ Cout, float* __restrict__ bn_sums)
{
  constexpr int NT = 4;                          // KDIM 256 / 64
  __shared__ unsigned short B_sh[128 * 64];      // [pix][k] bf16, XOR-swizzled
  __shared__ unsigned short xs[64 * 260];        // [ch][4 rows][64], stride 260 (bank-spread)
  __shared__ float kf_s[72];
  __shared__ float bn_lds[512];

  const int tid  = threadIdx.x;
  const int lane = tid & 63;
  const int wv   = tid >> 6;
  const int wm   = wv >> 1, wn = wv & 1;
  const int lr   = lane & 15, lg = lane >> 4;

  const int b    = blockIdx.x >> 5;
  const int R    = blockIdx.x & 31;              // pixel tile: image rows 2R, 2R+1
  const int pix0 = R << 7;
  const int g0   = R << 1;

  if (tid < 512) bn_lds[tid] = 0.f;
  if (tid < 72)  kf_s[tid] = kern[b * 72 + tid];
  __syncthreads();

  f32x4 acc[4][4] = {};
  const int c4 = tid & 15, q = tid >> 4;
  const int prow  = q >> 4;                      // 0|1 image row within tile
  const int pcol4 = (q & 15) << 2;               // col base 0..60
  const int grp9  = (c4 >> 3) * 9;               // kf sub-index (plus 2t*9 per tile)

  // staging map: flat = it*512+tid -> ch 0..63, r4 0..3, c8 0..7
  const int sch = tid >> 3, sr4 = ((tid & 7) >> 1), sc8h = tid & 1; // alt decode below
  const char* abase = (const char*)Afrag + wm * 8192 + lane * 16;

  bf16x8 aA[8];
  us8 rx[4];

  auto PREXS = [&](int t) {
    #pragma unroll
    for (int it = 0; it < 4; ++it) {
      int flat = it * 512 + tid;
      int ch = flat >> 5, r4 = (flat >> 3) & 3, c8 = flat & 7;
      int grow = g0 - 1 + r4;
      if ((unsigned)grow < 64u) {
        rx[it] = *(const us8*)(xt + ((size_t)(b * HID + t * 64 + ch) << 12) + grow * 64 + c8 * 8);
      } else {
        us8 z = {0, 0, 0, 0, 0, 0, 0, 0}; rx[it] = z;
      }
    }
  };
  auto WRXS = [&]() {
    #pragma unroll
    for (int it = 0; it < 4; ++it) {
      int flat = it * 512 + tid;
      int ch = flat >> 5, r4 = (flat >> 3) & 3, c8 = flat & 7;
      int o = ch * 260 + r4 * 64 + c8 * 8;
      *(us4*)(xs + o)     = *(const us4*)(&rx[it].v[0]);
      *(us4*)(xs + o + 4) = *(const us4*)(&rx[it].v[4]);
    }
  };
  auto ISSUE_A = [&](int t) {
    const char* p = abase + t * 32768;
    #pragma unroll
    for (int i = 0; i < 8; ++i) aA[i] = *(const bf16x8*)(p + i * 1024);
  };

  PREXS(0);
  ISSUE_A(0);

  for (int t = 0; t < NT; ++t) {
    WRXS();                                      // vmcnt wait inserted by compiler
    __syncthreads();
    if (t + 1 < NT) PREXS(t + 1);                // fly during dw-compute + MFMA
    // ---- depthwise 3x3 from xs -> B_sh (swizzled)
    {
      const float k0 = kf_s[2 * t * 9 + grp9 + 0], k1 = kf_s[2 * t * 9 + grp9 + 1], k2 = kf_s[2 * t * 9 + grp9 + 2];
      const float k3 = kf_s[2 * t * 9 + grp9 + 3], k4 = kf_s[2 * t * 9 + grp9 + 4], k5 = kf_s[2 * t * 9 + grp9 + 5];
      const float k6 = kf_s[2 * t * 9 + grp9 + 6], k7 = kf_s[2 * t * 9 + grp9 + 7], k8 = kf_s[2 * t * 9 + grp9 + 8];
      float dwv[4][4];
      #pragma unroll
      for (int i = 0; i < 4; ++i) {
        int ch = 4 * c4 + i;
        #pragma unroll
        for (int j = 0; j < 4; ++j) dwv[i][j] = 0.f;
        #pragma unroll
        for (int ky = 0; ky < 3; ++ky) {
          int ro = ch * 260 + (prow + ky) * 64;
          float v[6];
          unsigned int p0 = (pcol4 > 0)  ? *(const unsigned int*)(xs + ro + pcol4 - 2) : 0u;
          unsigned int p1 = *(const unsigned int*)(xs + ro + pcol4);
          unsigned int p2 = *(const unsigned int*)(xs + ro + pcol4 + 2);
          unsigned int p3 = (pcol4 < 60) ? *(const unsigned int*)(xs + ro + pcol4 + 4) : 0u;
          v[0] = bf2f((unsigned short)(p0 >> 16));
          v[1] = bf2f((unsigned short)(p1 & 0xffff));
          v[2] = bf2f((unsigned short)(p1 >> 16));
          v[3] = bf2f((unsigned short)(p2 & 0xffff));
          v[4] = bf2f((unsigned short)(p2 >> 16));
          v[5] = bf2f((unsigned short)(p3 & 0xffff));
          float ka = (ky == 0) ? k0 : (ky == 1) ? k3 : k6;
          float kb = (ky == 0) ? k1 : (ky == 1) ? k4 : k7;
          float kc = (ky == 0) ? k2 : (ky == 1) ? k5 : k8;
          #pragma unroll
          for (int j = 0; j < 4; ++j)
            dwv[i][j] += v[j] * ka + v[j + 1] * kb + v[j + 2] * kc;
        }
      }
      #pragma unroll
      for (int j = 0; j < 4; ++j) {
        int pix = 4 * q + j;
        us4 w = { f2bf(dwv[0][j]), f2bf(dwv[1][j]), f2bf(dwv[2][j]), f2bf(dwv[3][j]) };
        *(us4*)((char*)B_sh + pix * 128 + ((8 * c4) ^ ((pix & 7) << 4))) = w;
      }
    }
    __syncthreads();
    // ---- MFMA
    #pragma unroll
    for (int kk = 0; kk < 2; ++kk) {
      bf16x8 bfr[4];
      #pragma unroll
      for (int ni = 0; ni < 4; ++ni) {
        int pr = wn * 64 + ni * 16 + lr;
        bfr[ni] = *(const bf16x8*)((const char*)B_sh + pr * 128 + ((((kk << 2) | lg) ^ (pr & 7)) << 4));
      }
      #pragma unroll
      for (int mi = 0; mi < 4; ++mi)
        #pragma unroll
        for (int ni = 0; ni < 4; ++ni)
          acc[mi][ni] = __builtin_amdgcn_mfma_f32_16x16x32_bf16(aA[kk * 4 + mi], bfr[ni], acc[mi][ni], 0, 0, 0);
    }
    if (t + 1 < NT) ISSUE_A(t + 1);
  }

  // ---- epilogue: bias, bf16 store, BN partial stats
  #pragma unroll
  for (int mi = 0; mi < 4; ++mi) {
    #pragma unroll
    for (int r = 0; r < 4; ++r) {
      int o = wm * 64 + mi * 16 + lg * 4 + r;
      float bo = bias[o];
      #pragma unroll
      for (int ni = 0; ni < 4; ++ni) {
        int pix = pix0 + wn * 64 + ni * 16 + lr;
        float val = acc[mi][ni][r] + bo;
        Cout[((size_t)(b * HID + o)) * HW + pix] = f2bf(val);
        float s = val, s2 = val * val;
        #pragma unroll
        for (int msk = 1; msk < 16; msk <<= 1) {
          s  += __shfl_xor(s,  msk, 64);
          s2 += __shfl_xor(s2, msk, 64);
        }
        if (lr == 0) { atomicAdd(&bn_lds[o], s); atomicAdd(&bn_lds[256 + o], s2); }
      }
    }
  }
  __syncthreads();
  if (tid < 512) atomicAdd(&bn_sums[tid], bn_lds[tid]);
}

// wave-per-output FC layer: out[b][o] = act(scale * dot(in[b][:], w[o][:]) + bias[o])
template<int K, int N, bool RELU>
__global__ __launch_bounds__(256)
void fc_kernel(const float* __restrict__ in, const float* __restrict__ w,
               const float* __restrict__ bias, float* __restrict__ out, float scale)
{
  const int wid  = (blockIdx.x << 2) | (threadIdx.x >> 6);
  const int lane = threadIdx.x & 63;
  const int b = wid / N, o = wid - b * N;
  const float* ip = in + (size_t)b * K;
  const float* wp = w  + (size_t)o * K;
  float p = 0.f;
  #pragma unroll
  for (int k = 0; k < K / 64; ++k) p += ip[lane + k * 64] * wp[lane + k * 64];
  #pragma unroll
  for (int m = 1; m < 64; m <<= 1) p += __shfl_xor(p, m, 64);
  if (lane == 0) {
    float v = p * scale + bias[o];
    out[(size_t)b * N + o] = RELU ? fmaxf(v, 0.f) : v;
  }
}

// out = xt + scale[o]*ot + shift[o]; BN finalize folded in (per-block from bn_sums)
__global__ __launch_bounds__(256)
void final_kernel(const unsigned short* __restrict__ xt, const unsigned short* __restrict__ ot,
                  const float* __restrict__ bn_sums, const float* __restrict__ gamma,
                  const float* __restrict__ beta, float* __restrict__ out)
{
  __shared__ float sc_s[256], sh_s[256];
  {
    int t = threadIdx.x;
    const float inv_n = 1.f / 65536.f;          // B*H*W
    float m  = bn_sums[t] * inv_n;
    float v  = bn_sums[256 + t] * inv_n - m * m;
    float sc = gamma[t] * rsqrtf(v + 1e-5f);
    sc_s[t] = sc;
    sh_s[t] = beta[t] - m * sc;
  }
  __syncthreads();
  int g = blockIdx.x * 256 + threadIdx.x;       // group of 4 elements
  const int stride = 4096 * 256;
  #pragma unroll
  for (int it = 0; it < 4; ++it, g += stride) {
    int o = (g >> 10) & 255;
    us4 a = ((const us4*)xt)[g];
    us4 c = ((const us4*)ot)[g];
    float s = sc_s[o], h = sh_s[o];
    f4 r;
    #pragma unroll
    for (int j = 0; j < 4; ++j) r.v[j] = bf2f(a.v[j]) + s * bf2f(c.v[j]) + h;
    *(f4*)(out + (size_t)g * 4) = r;
  }
}

extern "C" void kernel_launch(void* const* d_in, const int* in_sizes, int n_in,
                              void* d_out, int out_size, void* d_ws, size_t ws_size,
                              hipStream_t stream)
{
  const float* x     = (const float*)d_in[0];
  const float* ctx_w = (const float*)d_in[1];
  const float* ctx_b = (const float*)d_in[2];
  const float* kg_w1 = (const float*)d_in[3];
  const float* kg_b1 = (const float*)d_in[4];
  const float* kg_w2 = (const float*)d_in[5];
  const float* kg_b2 = (const float*)d_in[6];
  const float* in_w  = (const float*)d_in[7];
  const float* in_b  = (const float*)d_in[8];
  const float* out_w = (const float*)d_in[9];
  const float* out_b = (const float*)d_in[10];
  const float* gamma = (const float*)d_in[11];
  const float* beta  = (const float*)d_in[12];
  float* out = (float*)d_out;

  char* ws = (char*)d_ws;
  unsigned short* xt = (unsigned short*)ws;                  // 32 MiB bf16 xt
  unsigned short* ot = (unsigned short*)(ws + 33554432);     // 32 MiB bf16 out_trans
  float* ctx_sum = (float*)(ws + 67108864);                  // [16][1024]
  float* bn_sums = ctx_sum + 16384;                          // [512] (zeroed by prep)
  float* kern    = bn_sums + 512;                            // [16][72]
  float* ctxbuf  = kern + 1152;                              // [16][256]
  float* hddnbuf = ctxbuf + 4096;                            // [16][512]
  unsigned short* afrag1 = (unsigned short*)(ws + 67108864 + 131072);            // 512 KiB
  unsigned short* afrag2 = (unsigned short*)(ws + 67108864 + 131072 + 524288);   // 128 KiB

  prep_kernel<<<226, 256, 0, stream>>>(in_w, afrag1, out_w, afrag2, ctx_sum);
  gemm_kernel<1024, false, true, false><<<512, 512, 0, stream>>>(afrag1, x, in_b, xt, ctx_sum, nullptr);
  fc_kernel<1024, 256, true ><<<1024, 256, 0, stream>>>(ctx_sum, ctx_w, ctx_b, ctxbuf, 1.f / 4096.f);
  fc_kernel< 256, 512, true ><<<2048, 256, 0, stream>>>(ctxbuf,  kg_w1, kg_b1, hddnbuf, 1.f);
  fc_kernel< 512,  72, false><<< 288, 256, 0, stream>>>(hddnbuf, kg_w2, kg_b2, kern,    1.f);
  gemm2_fused_kernel<<<512, 512, 0, stream>>>(afrag2, xt, kern, out_b, ot, bn_sums);
  final_kernel<<<4096, 256, 0, stream>>>(xt, ot, bn_sums, gamma, beta, out);
}

// Round 7
// 195.524 us; speedup vs baseline: 1.5614x; 1.0871x over previous
//
#include <hip/hip_runtime.h>

#define BATCH 16
#define CIN   1024
#define HID   256
#define HW    4096

typedef __attribute__((ext_vector_type(8))) short bf16x8;
typedef __attribute__((ext_vector_type(4))) float f32x4;

struct __align__(16) f4  { float v[4]; };
struct __align__(8)  us4 { unsigned short v[4]; };
struct __align__(16) us8 { unsigned short v[8]; };

__device__ __forceinline__ float bf2f(unsigned short u) {
  unsigned int x = ((unsigned int)u) << 16;
  return __builtin_bit_cast(float, x);
}
__device__ __forceinline__ unsigned short f2bf(float f) {
  unsigned int u = __builtin_bit_cast(unsigned int, f);
  u += 0x7fff + ((u >> 16) & 1);            // round-to-nearest-even
  return (unsigned short)(u >> 16);
}

// lgkm-only barrier: drain ds ops, leave ALL vmem prefetch in flight
#define LGWB() do { __builtin_amdgcn_sched_barrier(0); \
  asm volatile("s_waitcnt lgkmcnt(0)" ::: "memory"); \
  __builtin_amdgcn_s_barrier(); \
  __builtin_amdgcn_sched_barrier(0); } while (0)

// Pre-convert fp32 [256][KD] weights into per-lane bf16 MFMA A-fragments:
// unit u -> [tile][wm][kk][mi][lane], 16 B each. Trailing blocks zero ctx/bn sums.
__global__ __launch_bounds__(256)
void prep_kernel(const float* __restrict__ A1, unsigned short* __restrict__ O1,
                 const float* __restrict__ A2, unsigned short* __restrict__ O2,
                 float* __restrict__ zbuf)
{
  const int bidx = blockIdx.x;
  if (bidx >= 160) {                        // zero ctx_sum[16384] + bn_sums[512]
    int idx = (bidx - 160) * 256 + threadIdx.x;
    if (idx < 16896) zbuf[idx] = 0.f;
    return;
  }
  const float* A; unsigned short* O; int KD, u;
  if (bidx < 128) { A = A1; O = O1; KD = 1024; u = bidx * 256 + threadIdx.x; }
  else            { A = A2; O = O2; KD = 256;  u = (bidx - 128) * 256 + threadIdx.x; }
  const int t    = u >> 11;                 // K-tile (2048 units of 16 B per tile)
  const int r    = u & 2047;
  const int wm   = r >> 9, kk = (r >> 8) & 1, mi = (r >> 6) & 3, lane = r & 63;
  const int row  = wm * 64 + mi * 16 + (lane & 15);
  const int k    = t * 64 + kk * 32 + (lane >> 4) * 8;
  f4 v0 = *(const f4*)(A + (size_t)row * KD + k);
  f4 v1 = *(const f4*)(A + (size_t)row * KD + k + 4);
  us8 w = { f2bf(v0.v[0]), f2bf(v0.v[1]), f2bf(v0.v[2]), f2bf(v0.v[3]),
            f2bf(v1.v[0]), f2bf(v1.v[1]), f2bf(v1.v[2]), f2bf(v1.v[3]) };
  *(us8*)(O + (size_t)u * 8) = w;
}

// ============ GEMM1: xt[b][m][pix] = sum_k in_w[m][k]*x[b][k][pix] + bias[m] ====
// Contiguous staging: per wave-instr, 2 x 512-B global segments (2 ch rows).
// Thread: ch {8wv+2i+hi}, px 4q..4q+3. cvt_pk -> shfl_xor(32) pairs ch 2i/2i+1 ->
// thread owns quad c4e=2wv+hi x 4 px. LDS slot swizzle: P ^ (((pix>>2)^pix)&7),
// 2-way (free) on both write and read phases. No vmem drain in the K-loop.
__global__ __launch_bounds__(512, 2)
void gemm1_kernel(const unsigned short* __restrict__ Afrag, const float* __restrict__ xb,
                  const float* __restrict__ bias, unsigned short* __restrict__ Cout,
                  float* __restrict__ ctx_sum)
{
  constexpr int NT = 16;
  __shared__ unsigned short B_sh[2][128 * 64];   // [pix] rows of 8 swizzled 16-B slots
  __shared__ float ctx_lds[1024];

  const int tid  = threadIdx.x;
  const int lane = tid & 63;
  const int wv   = tid >> 6;
  const int wm   = wv >> 1, wn = wv & 1;         // wave grid 4(M) x 2(N), tile 64x64
  const int lr   = lane & 15, lg = lane >> 4;
  const int hi   = lane >> 5, q = lane & 31;

  const int b    = blockIdx.x >> 5;
  const int pix0 = (blockIdx.x & 31) << 7;

  for (int i = tid; i < 1024; i += 512) ctx_lds[i] = 0.f;
  __syncthreads();

  f32x4 acc[4][4] = {};
  const size_t rowbase = ((size_t)b * CIN + 8 * wv + hi) * HW + pix0 + 4 * q;
  const char*  abase   = (const char*)Afrag + wm * 8192 + lane * 16;

  bf16x8 aA[8], aB[8];                           // A frag double-buffer (regs)
  f4 rfA[4], rfB[4];                             // B prefetch sets

  auto ISSUE_A = [&](int t, bf16x8* a) {
    const char* p = abase + t * 32768;
    #pragma unroll
    for (int i = 0; i < 8; ++i) a[i] = *(const bf16x8*)(p + i * 1024);
  };
  auto LOADB = [&](int t, f4* rf) {
    const float* p = xb + rowbase + (size_t)t * 64 * HW;
    #pragma unroll
    for (int i = 0; i < 4; ++i) rf[i] = *(const f4*)(p + (size_t)(2 * i) * HW);
  };
  auto WRITEB = [&](int sel, int t, f4* rf) {
    // fused context-pool partial sums (each x element staged once)
    #pragma unroll
    for (int i = 0; i < 4; ++i) {
      float s = rf[i].v[0] + rf[i].v[1] + rf[i].v[2] + rf[i].v[3];
      #pragma unroll
      for (int m = 1; m < 32; m <<= 1) s += __shfl_xor(s, m, 64);
      if (q == 0) atomicAdd(&ctx_lds[t * 64 + 8 * wv + 2 * i + hi], s);
    }
    unsigned int u[4][2];
    #pragma unroll
    for (int i = 0; i < 4; ++i) {
      asm("v_cvt_pk_bf16_f32 %0, %1, %2" : "=v"(u[i][0]) : "v"(rf[i].v[0]), "v"(rf[i].v[1]));
      asm("v_cvt_pk_bf16_f32 %0, %1, %2" : "=v"(u[i][1]) : "v"(rf[i].v[2]), "v"(rf[i].v[3]));
    }
    unsigned int w[4][2];
    #pragma unroll
    for (int i = 0; i < 4; ++i) {
      w[i][0] = __shfl_xor(u[i][0], 32, 64);
      w[i][1] = __shfl_xor(u[i][1], 32, 64);
    }
    // ch-ordered quad (offsets 0..3): hi=0 -> [u0,w0,u1,w1]; hi=1 -> [w2,u2,w3,u3]
    #pragma unroll
    for (int jj = 0; jj < 2; ++jj) {
      unsigned int A0 = hi ? w[2][jj] : u[0][jj];
      unsigned int A1 = hi ? u[2][jj] : w[0][jj];
      unsigned int A2 = hi ? w[3][jj] : u[1][jj];
      unsigned int A3 = hi ? u[3][jj] : w[1][jj];
      #pragma unroll
      for (int sub = 0; sub < 2; ++sub) {
        unsigned int lo, h2;
        if (sub == 0) { lo = (A0 & 0xffffu) | (A1 << 16);  h2 = (A2 & 0xffffu) | (A3 << 16); }
        else          { lo = (A0 >> 16) | (A1 & 0xffff0000u); h2 = (A2 >> 16) | (A3 & 0xffff0000u); }
        int p  = 4 * q + jj * 2 + sub;
        int fx = ((p >> 2) ^ p) & 7;
        int byte = p * 128 + (((wv ^ fx) & 7) << 4) + hi * 8;
        uint2 val; val.x = lo; val.y = h2;
        *(uint2*)((char*)B_sh[sel] + byte) = val;
      }
    }
  };
  auto COMPUTE = [&](int sel, bf16x8* a) {
    #pragma unroll
    for (int kk = 0; kk < 2; ++kk) {
      bf16x8 bfr[4];
      #pragma unroll
      for (int ni = 0; ni < 4; ++ni) {
        int pr = wn * 64 + ni * 16 + lr;
        int fx = ((pr >> 2) ^ pr) & 7;
        int byte = pr * 128 + ((((kk * 4 + lg) ^ fx) & 7) << 4);
        bfr[ni] = *(const bf16x8*)((const char*)B_sh[sel] + byte);
      }
      #pragma unroll
      for (int mi = 0; mi < 4; ++mi)
        #pragma unroll
        for (int ni = 0; ni < 4; ++ni)
          acc[mi][ni] = __builtin_amdgcn_mfma_f32_16x16x32_bf16(a[kk * 4 + mi], bfr[ni], acc[mi][ni], 0, 0, 0);
    }
  };

  // prologue: A(0) + B(0),B(1) in flight
  ISSUE_A(0, aA);
  LOADB(0, rfA);
  LOADB(1, rfB);

  #pragma unroll
  for (int t = 0; t < NT; t += 2) {
    WRITEB(0, t, rfA);
    if (t + 2 < NT) LOADB(t + 2, rfA);
    ISSUE_A(t + 1, aB);
    LGWB();
    COMPUTE(0, aA);
    WRITEB(1, t + 1, rfB);
    if (t + 3 < NT) LOADB(t + 3, rfB);
    if (t + 2 < NT) ISSUE_A(t + 2, aA);
    LGWB();
    COMPUTE(1, aB);
  }

  // ---- epilogue: bias, bf16 store
  #pragma unroll
  for (int mi = 0; mi < 4; ++mi) {
    #pragma unroll
    for (int r = 0; r < 4; ++r) {
      int o = wm * 64 + mi * 16 + lg * 4 + r;   // C/D: col=lane&15, row=(lane>>4)*4+reg
      float bo = bias[o];
      #pragma unroll
      for (int ni = 0; ni < 4; ++ni) {
        int pix = pix0 + wn * 64 + ni * 16 + lr;
        Cout[((size_t)(b * HID + o)) * HW + pix] = f2bf(acc[mi][ni][r] + bo);
      }
    }
  }
  __syncthreads();
  for (int e = tid; e < 1024; e += 512)
    atomicAdd(&ctx_sum[(size_t)b * 1024 + e], ctx_lds[e]);
}

// ============ GEMM2 fused with depthwise conv ============
// out_trans[b][o][pix] = sum_ch out_w[o][ch] * dw[b][ch][pix] + out_b[o]
// dw computed on the fly from xt (LDS slab: 64 ch x 4 rows x 64 cols per k-tile).
__global__ __launch_bounds__(512, 2)
void gemm2_fused_kernel(const unsigned short* __restrict__ Afrag,
                        const unsigned short* __restrict__ xt,
                        const float* __restrict__ kern, const float* __restrict__ bias,
                        unsigned short* __restrict__ Cout, float* __restrict__ bn_sums)
{
  constexpr int NT = 4;                          // KDIM 256 / 64
  __shared__ unsigned short B_sh[128 * 64];      // [pix][k] bf16, XOR-swizzled
  __shared__ unsigned short xs[64 * 260];        // [ch][4 rows][64], stride 260 (bank-spread)
  __shared__ float kf_s[72];
  __shared__ float bn_lds[512];

  const int tid  = threadIdx.x;
  const int lane = tid & 63;
  const int wv   = tid >> 6;
  const int wm   = wv >> 1, wn = wv & 1;
  const int lr   = lane & 15, lg = lane >> 4;

  const int b    = blockIdx.x >> 5;
  const int R    = blockIdx.x & 31;              // pixel tile: image rows 2R, 2R+1
  const int pix0 = R << 7;
  const int g0   = R << 1;

  if (tid < 512) bn_lds[tid] = 0.f;
  if (tid < 72)  kf_s[tid] = kern[b * 72 + tid];
  __syncthreads();

  f32x4 acc[4][4] = {};
  const int c4 = tid & 15, q = tid >> 4;
  const int prow  = q >> 4;                      // 0|1 image row within tile
  const int pcol4 = (q & 15) << 2;               // col base 0..60
  const int grp9  = (c4 >> 3) * 9;               // kf sub-index (plus 2t*9 per tile)

  const char* abase = (const char*)Afrag + wm * 8192 + lane * 16;

  bf16x8 aA[8];
  us8 rx[4];

  auto PREXS = [&](int t) {
    #pragma unroll
    for (int it = 0; it < 4; ++it) {
      int flat = it * 512 + tid;
      int ch = flat >> 5, r4 = (flat >> 3) & 3, c8 = flat & 7;
      int grow = g0 - 1 + r4;
      if ((unsigned)grow < 64u) {
        rx[it] = *(const us8*)(xt + ((size_t)(b * HID + t * 64 + ch) << 12) + grow * 64 + c8 * 8);
      } else {
        us8 z = {0, 0, 0, 0, 0, 0, 0, 0}; rx[it] = z;
      }
    }
  };
  auto WRXS = [&]() {
    #pragma unroll
    for (int it = 0; it < 4; ++it) {
      int flat = it * 512 + tid;
      int ch = flat >> 5, r4 = (flat >> 3) & 3, c8 = flat & 7;
      int o = ch * 260 + r4 * 64 + c8 * 8;
      *(us4*)(xs + o)     = *(const us4*)(&rx[it].v[0]);
      *(us4*)(xs + o + 4) = *(const us4*)(&rx[it].v[4]);
    }
  };
  auto ISSUE_A = [&](int t) {
    const char* p = abase + t * 32768;
    #pragma unroll
    for (int i = 0; i < 8; ++i) aA[i] = *(const bf16x8*)(p + i * 1024);
  };

  PREXS(0);
  ISSUE_A(0);

  for (int t = 0; t < NT; ++t) {
    WRXS();                                      // vmcnt wait inserted by compiler
    __syncthreads();
    if (t + 1 < NT) PREXS(t + 1);                // fly during dw-compute + MFMA
    // ---- depthwise 3x3 from xs -> B_sh (swizzled)
    {
      const float k0 = kf_s[2 * t * 9 + grp9 + 0], k1 = kf_s[2 * t * 9 + grp9 + 1], k2 = kf_s[2 * t * 9 + grp9 + 2];
      const float k3 = kf_s[2 * t * 9 + grp9 + 3], k4 = kf_s[2 * t * 9 + grp9 + 4], k5 = kf_s[2 * t * 9 + grp9 + 5];
      const float k6 = kf_s[2 * t * 9 + grp9 + 6], k7 = kf_s[2 * t * 9 + grp9 + 7], k8 = kf_s[2 * t * 9 + grp9 + 8];
      float dwv[4][4];
      #pragma unroll
      for (int i = 0; i < 4; ++i) {
        int ch = 4 * c4 + i;
        #pragma unroll
        for (int j = 0; j < 4; ++j) dwv[i][j] = 0.f;
        #pragma unroll
        for (int ky = 0; ky < 3; ++ky) {
          int ro = ch * 260 + (prow + ky) * 64;
          float v[6];
          unsigned int p0 = (pcol4 > 0)  ? *(const unsigned int*)(xs + ro + pcol4 - 2) : 0u;
          unsigned int p1 = *(const unsigned int*)(xs + ro + pcol4);
          unsigned int p2 = *(const unsigned int*)(xs + ro + pcol4 + 2);
          unsigned int p3 = (pcol4 < 60) ? *(const unsigned int*)(xs + ro + pcol4 + 4) : 0u;
          v[0] = bf2f((unsigned short)(p0 >> 16));
          v[1] = bf2f((unsigned short)(p1 & 0xffff));
          v[2] = bf2f((unsigned short)(p1 >> 16));
          v[3] = bf2f((unsigned short)(p2 & 0xffff));
          v[4] = bf2f((unsigned short)(p2 >> 16));
          v[5] = bf2f((unsigned short)(p3 & 0xffff));
          float ka = (ky == 0) ? k0 : (ky == 1) ? k3 : k6;
          float kb = (ky == 0) ? k1 : (ky == 1) ? k4 : k7;
          float kc = (ky == 0) ? k2 : (ky == 1) ? k5 : k8;
          #pragma unroll
          for (int j = 0; j < 4; ++j)
            dwv[i][j] += v[j] * ka + v[j + 1] * kb + v[j + 2] * kc;
        }
      }
      #pragma unroll
      for (int j = 0; j < 4; ++j) {
        int pix = 4 * q + j;
        us4 w = { f2bf(dwv[0][j]), f2bf(dwv[1][j]), f2bf(dwv[2][j]), f2bf(dwv[3][j]) };
        *(us4*)((char*)B_sh + pix * 128 + ((8 * c4) ^ ((pix & 7) << 4))) = w;
      }
    }
    __syncthreads();
    // ---- MFMA
    #pragma unroll
    for (int kk = 0; kk < 2; ++kk) {
      bf16x8 bfr[4];
      #pragma unroll
      for (int ni = 0; ni < 4; ++ni) {
        int pr = wn * 64 + ni * 16 + lr;
        bfr[ni] = *(const bf16x8*)((const char*)B_sh + pr * 128 + ((((kk << 2) | lg) ^ (pr & 7)) << 4));
      }
      #pragma unroll
      for (int mi = 0; mi < 4; ++mi)
        #pragma unroll
        for (int ni = 0; ni < 4; ++ni)
          acc[mi][ni] = __builtin_amdgcn_mfma_f32_16x16x32_bf16(aA[kk * 4 + mi], bfr[ni], acc[mi][ni], 0, 0, 0);
    }
    if (t + 1 < NT) ISSUE_A(t + 1);
  }

  // ---- epilogue: bias, bf16 store, BN partial stats
  #pragma unroll
  for (int mi = 0; mi < 4; ++mi) {
    #pragma unroll
    for (int r = 0; r < 4; ++r) {
      int o = wm * 64 + mi * 16 + lg * 4 + r;
      float bo = bias[o];
      #pragma unroll
      for (int ni = 0; ni < 4; ++ni) {
        int pix = pix0 + wn * 64 + ni * 16 + lr;
        float val = acc[mi][ni][r] + bo;
        Cout[((size_t)(b * HID + o)) * HW + pix] = f2bf(val);
        float s = val, s2 = val * val;
        #pragma unroll
        for (int msk = 1; msk < 16; msk <<= 1) {
          s  += __shfl_xor(s,  msk, 64);
          s2 += __shfl_xor(s2, msk, 64);
        }
        if (lr == 0) { atomicAdd(&bn_lds[o], s); atomicAdd(&bn_lds[256 + o], s2); }
      }
    }
  }
  __syncthreads();
  if (tid < 512) atomicAdd(&bn_sums[tid], bn_lds[tid]);
}

// wave-per-output FC layer: out[b][o] = act(scale * dot(in[b][:], w[o][:]) + bias[o])
template<int K, int N, bool RELU>
__global__ __launch_bounds__(256)
void fc_kernel(const float* __restrict__ in, const float* __restrict__ w,
               const float* __restrict__ bias, float* __restrict__ out, float scale)
{
  const int wid  = (blockIdx.x << 2) | (threadIdx.x >> 6);
  const int lane = threadIdx.x & 63;
  const int b = wid / N, o = wid - b * N;
  const float* ip = in + (size_t)b * K;
  const float* wp = w  + (size_t)o * K;
  float p = 0.f;
  #pragma unroll
  for (int k = 0; k < K / 64; ++k) p += ip[lane + k * 64] * wp[lane + k * 64];
  #pragma unroll
  for (int m = 1; m < 64; m <<= 1) p += __shfl_xor(p, m, 64);
  if (lane == 0) {
    float v = p * scale + bias[o];
    out[(size_t)b * N + o] = RELU ? fmaxf(v, 0.f) : v;
  }
}

// out = xt + scale[o]*ot + shift[o]; BN finalize folded in (per-block from bn_sums)
__global__ __launch_bounds__(256)
void final_kernel(const unsigned short* __restrict__ xt, const unsigned short* __restrict__ ot,
                  const float* __restrict__ bn_sums, const float* __restrict__ gamma,
                  const float* __restrict__ beta, float* __restrict__ out)
{
  __shared__ float sc_s[256], sh_s[256];
  {
    int t = threadIdx.x;
    const float inv_n = 1.f / 65536.f;          // B*H*W
    float m  = bn_sums[t] * inv_n;
    float v  = bn_sums[256 + t] * inv_n - m * m;
    float sc = gamma[t] * rsqrtf(v + 1e-5f);
    sc_s[t] = sc;
    sh_s[t] = beta[t] - m * sc;
  }
  __syncthreads();
  int g = blockIdx.x * 256 + threadIdx.x;       // group of 4 elements
  const int stride = 4096 * 256;
  #pragma unroll
  for (int it = 0; it < 4; ++it, g += stride) {
    int o = (g >> 10) & 255;
    us4 a = ((const us4*)xt)[g];
    us4 c = ((const us4*)ot)[g];
    float s = sc_s[o], h = sh_s[o];
    f4 r;
    #pragma unroll
    for (int j = 0; j < 4; ++j) r.v[j] = bf2f(a.v[j]) + s * bf2f(c.v[j]) + h;
    *(f4*)(out + (size_t)g * 4) = r;
  }
}

extern "C" void kernel_launch(void* const* d_in, const int* in_sizes, int n_in,
                              void* d_out, int out_size, void* d_ws, size_t ws_size,
                              hipStream_t stream)
{
  const float* x     = (const float*)d_in[0];
  const float* ctx_w = (const float*)d_in[1];
  const float* ctx_b = (const float*)d_in[2];
  const float* kg_w1 = (const float*)d_in[3];
  const float* kg_b1 = (const float*)d_in[4];
  const float* kg_w2 = (const float*)d_in[5];
  const float* kg_b2 = (const float*)d_in[6];
  const float* in_w  = (const float*)d_in[7];
  const float* in_b  = (const float*)d_in[8];
  const float* out_w = (const float*)d_in[9];
  const float* out_b = (const float*)d_in[10];
  const float* gamma = (const float*)d_in[11];
  const float* beta  = (const float*)d_in[12];
  float* out = (float*)d_out;

  char* ws = (char*)d_ws;
  unsigned short* xt = (unsigned short*)ws;                  // 32 MiB bf16 xt
  unsigned short* ot = (unsigned short*)(ws + 33554432);     // 32 MiB bf16 out_trans
  float* ctx_sum = (float*)(ws + 67108864);                  // [16][1024]
  float* bn_sums = ctx_sum + 16384;                          // [512] (zeroed by prep)
  float* kern    = bn_sums + 512;                            // [16][72]
  float* ctxbuf  = kern + 1152;                              // [16][256]
  float* hddnbuf = ctxbuf + 4096;                            // [16][512]
  unsigned short* afrag1 = (unsigned short*)(ws + 67108864 + 131072);            // 512 KiB
  unsigned short* afrag2 = (unsigned short*)(ws + 67108864 + 131072 + 524288);   // 128 KiB

  prep_kernel<<<226, 256, 0, stream>>>(in_w, afrag1, out_w, afrag2, ctx_sum);
  gemm1_kernel<<<512, 512, 0, stream>>>(afrag1, x, in_b, xt, ctx_sum);
  fc_kernel<1024, 256, true ><<<1024, 256, 0, stream>>>(ctx_sum, ctx_w, ctx_b, ctxbuf, 1.f / 4096.f);
  fc_kernel< 256, 512, true ><<<2048, 256, 0, stream>>>(ctxbuf,  kg_w1, kg_b1, hddnbuf, 1.f);
  fc_kernel< 512,  72, false><<< 288, 256, 0, stream>>>(hddnbuf, kg_w2, kg_b2, kern,    1.f);
  gemm2_fused_kernel<<<512, 512, 0, stream>>>(afrag2, xt, kern, out_b, ot, bn_sums);
  final_kernel<<<4096, 256, 0, stream>>>(xt, ot, bn_sums, gamma, beta, out);
}

// Round 8
// 185.461 us; speedup vs baseline: 1.6461x; 1.0543x over previous
//
#include <hip/hip_runtime.h>

#define BATCH 16
#define CIN   1024
#define HID   256
#define HW    4096

typedef __attribute__((ext_vector_type(8))) short bf16x8;
typedef __attribute__((ext_vector_type(4))) float f32x4;

struct __align__(16) f4  { float v[4]; };
struct __align__(8)  us4 { unsigned short v[4]; };
struct __align__(16) us8 { unsigned short v[8]; };

__device__ __forceinline__ float bf2f(unsigned short u) {
  unsigned int x = ((unsigned int)u) << 16;
  return __builtin_bit_cast(float, x);
}
__device__ __forceinline__ unsigned short f2bf(float f) {
  unsigned int u = __builtin_bit_cast(unsigned int, f);
  u += 0x7fff + ((u >> 16) & 1);            // round-to-nearest-even
  return (unsigned short)(u >> 16);
}

// lgkm-only barrier: drain ds ops, leave ALL vmem prefetch in flight
#define LGWB() do { __builtin_amdgcn_sched_barrier(0); \
  asm volatile("s_waitcnt lgkmcnt(0)" ::: "memory"); \
  __builtin_amdgcn_s_barrier(); \
  __builtin_amdgcn_sched_barrier(0); } while (0)

// Pre-convert fp32 [256][KD] weights into per-lane bf16 MFMA A-fragments:
// unit u -> [tile][wm][kk][mi][lane], 16 B each. Trailing blocks zero ctx/bn sums.
__global__ __launch_bounds__(256)
void prep_kernel(const float* __restrict__ A1, unsigned short* __restrict__ O1,
                 const float* __restrict__ A2, unsigned short* __restrict__ O2,
                 float* __restrict__ zbuf)
{
  const int bidx = blockIdx.x;
  if (bidx >= 160) {                        // zero ctx_sum[16384] + bn_sums[512]
    int idx = (bidx - 160) * 256 + threadIdx.x;
    if (idx < 16896) zbuf[idx] = 0.f;
    return;
  }
  const float* A; unsigned short* O; int KD, u;
  if (bidx < 128) { A = A1; O = O1; KD = 1024; u = bidx * 256 + threadIdx.x; }
  else            { A = A2; O = O2; KD = 256;  u = (bidx - 128) * 256 + threadIdx.x; }
  const int t    = u >> 11;                 // K-tile (2048 units of 16 B per tile)
  const int r    = u & 2047;
  const int wm   = r >> 9, kk = (r >> 8) & 1, mi = (r >> 6) & 3, lane = r & 63;
  const int row  = wm * 64 + mi * 16 + (lane & 15);
  const int k    = t * 64 + kk * 32 + (lane >> 4) * 8;
  f4 v0 = *(const f4*)(A + (size_t)row * KD + k);
  f4 v1 = *(const f4*)(A + (size_t)row * KD + k + 4);
  us8 w = { f2bf(v0.v[0]), f2bf(v0.v[1]), f2bf(v0.v[2]), f2bf(v0.v[3]),
            f2bf(v1.v[0]), f2bf(v1.v[1]), f2bf(v1.v[2]), f2bf(v1.v[3]) };
  *(us8*)(O + (size_t)u * 8) = w;
}

// ============ GEMM1: xt[b][m][pix] = sum_k in_w[m][k]*x[b][k][pix] + bias[m] ====
// Contiguous staging (2 x 512-B segs/instr), cvt_pk+shfl transpose, swizzled LDS.
// T4 discipline: ISSUE_A pinned BEFORE LOADB each half so the MFMA's vmcnt wait
// (FIFO!) never retires the HBM B-prefetch; vmem never drains in the K-loop.
__global__ __launch_bounds__(512, 2)
void gemm1_kernel(const unsigned short* __restrict__ Afrag, const float* __restrict__ xb,
                  const float* __restrict__ bias, unsigned short* __restrict__ Cout,
                  float* __restrict__ ctx_sum)
{
  constexpr int NT = 16;
  __shared__ unsigned short B_sh[2][128 * 64];   // [pix] rows of 8 swizzled 16-B slots
  __shared__ float ctx_lds[1024];

  const int tid  = threadIdx.x;
  const int lane = tid & 63;
  const int wv   = tid >> 6;
  const int wm   = wv >> 1, wn = wv & 1;         // wave grid 4(M) x 2(N), tile 64x64
  const int lr   = lane & 15, lg = lane >> 4;
  const int hi   = lane >> 5, q = lane & 31;

  const int b    = blockIdx.x >> 5;
  const int pix0 = (blockIdx.x & 31) << 7;

  for (int i = tid; i < 1024; i += 512) ctx_lds[i] = 0.f;
  __syncthreads();

  f32x4 acc[4][4] = {};
  const size_t rowbase = ((size_t)b * CIN + 8 * wv + hi) * HW + pix0 + 4 * q;
  const char*  abase   = (const char*)Afrag + wm * 8192 + lane * 16;

  bf16x8 aA[8], aB[8];                           // A frag double-buffer (regs)
  f4 rfA[4], rfB[4];                             // B prefetch sets

  auto ISSUE_A = [&](int t, bf16x8* a) {
    const char* p = abase + t * 32768;
    #pragma unroll
    for (int i = 0; i < 8; ++i) a[i] = *(const bf16x8*)(p + i * 1024);
  };
  auto LOADB = [&](int t, f4* rf) {
    const float* p = xb + rowbase + (size_t)t * 64 * HW;
    #pragma unroll
    for (int i = 0; i < 4; ++i) rf[i] = *(const f4*)(p + (size_t)(2 * i) * HW);
  };
  auto WRITEB = [&](int sel, int t, f4* rf) {
    // fused context-pool partial sums (each x element staged once)
    #pragma unroll
    for (int i = 0; i < 4; ++i) {
      float s = rf[i].v[0] + rf[i].v[1] + rf[i].v[2] + rf[i].v[3];
      #pragma unroll
      for (int m = 1; m < 32; m <<= 1) s += __shfl_xor(s, m, 64);
      if (q == 0) atomicAdd(&ctx_lds[t * 64 + 8 * wv + 2 * i + hi], s);
    }
    unsigned int u[4][2];
    #pragma unroll
    for (int i = 0; i < 4; ++i) {
      asm("v_cvt_pk_bf16_f32 %0, %1, %2" : "=v"(u[i][0]) : "v"(rf[i].v[0]), "v"(rf[i].v[1]));
      asm("v_cvt_pk_bf16_f32 %0, %1, %2" : "=v"(u[i][1]) : "v"(rf[i].v[2]), "v"(rf[i].v[3]));
    }
    unsigned int w[4][2];
    #pragma unroll
    for (int i = 0; i < 4; ++i) {
      w[i][0] = __shfl_xor(u[i][0], 32, 64);
      w[i][1] = __shfl_xor(u[i][1], 32, 64);
    }
    // ch-ordered quad (offsets 0..3): hi=0 -> [u0,w0,u1,w1]; hi=1 -> [w2,u2,w3,u3]
    #pragma unroll
    for (int jj = 0; jj < 2; ++jj) {
      unsigned int A0 = hi ? w[2][jj] : u[0][jj];
      unsigned int A1 = hi ? u[2][jj] : w[0][jj];
      unsigned int A2 = hi ? w[3][jj] : u[1][jj];
      unsigned int A3 = hi ? u[3][jj] : w[1][jj];
      #pragma unroll
      for (int sub = 0; sub < 2; ++sub) {
        unsigned int lo, h2;
        if (sub == 0) { lo = (A0 & 0xffffu) | (A1 << 16);  h2 = (A2 & 0xffffu) | (A3 << 16); }
        else          { lo = (A0 >> 16) | (A1 & 0xffff0000u); h2 = (A2 >> 16) | (A3 & 0xffff0000u); }
        int p  = 4 * q + jj * 2 + sub;
        int fx = ((p >> 2) ^ p) & 7;
        int byte = p * 128 + (((wv ^ fx) & 7) << 4) + hi * 8;
        uint2 val; val.x = lo; val.y = h2;
        *(uint2*)((char*)B_sh[sel] + byte) = val;
      }
    }
  };
  auto COMPUTE = [&](int sel, bf16x8* a) {
    #pragma unroll
    for (int kk = 0; kk < 2; ++kk) {
      bf16x8 bfr[4];
      #pragma unroll
      for (int ni = 0; ni < 4; ++ni) {
        int pr = wn * 64 + ni * 16 + lr;
        int fx = ((pr >> 2) ^ pr) & 7;
        int byte = pr * 128 + ((((kk * 4 + lg) ^ fx) & 7) << 4);
        bfr[ni] = *(const bf16x8*)((const char*)B_sh[sel] + byte);
      }
      #pragma unroll
      for (int mi = 0; mi < 4; ++mi)
        #pragma unroll
        for (int ni = 0; ni < 4; ++ni)
          acc[mi][ni] = __builtin_amdgcn_mfma_f32_16x16x32_bf16(a[kk * 4 + mi], bfr[ni], acc[mi][ni], 0, 0, 0);
    }
  };

  // prologue: A(0) + B(0),B(1) in flight
  ISSUE_A(0, aA);
  LOADB(0, rfA);
  LOADB(1, rfB);

  #pragma unroll
  for (int t = 0; t < NT; t += 2) {
    // ---- half 1: tile t (B_sh[0], aA). A-issue BEFORE B-issue (FIFO discipline).
    WRITEB(0, t, rfA);
    ISSUE_A(t + 1, aB);
    __builtin_amdgcn_sched_barrier(0);           // pin: aB loads older than LOADB(t+2)
    if (t + 2 < NT) LOADB(t + 2, rfA);
    LGWB();
    COMPUTE(0, aA);                              // waits aA only; B prefetch stays in flight
    // ---- half 2: tile t+1 (B_sh[1], aB)
    WRITEB(1, t + 1, rfB);
    if (t + 2 < NT) ISSUE_A(t + 2, aA);
    __builtin_amdgcn_sched_barrier(0);           // pin: aA loads older than LOADB(t+3)
    if (t + 3 < NT) LOADB(t + 3, rfB);
    LGWB();
    COMPUTE(1, aB);                              // waits aB only
  }

  // ---- epilogue: bias, bf16 store
  #pragma unroll
  for (int mi = 0; mi < 4; ++mi) {
    #pragma unroll
    for (int r = 0; r < 4; ++r) {
      int o = wm * 64 + mi * 16 + lg * 4 + r;   // C/D: col=lane&15, row=(lane>>4)*4+reg
      float bo = bias[o];
      #pragma unroll
      for (int ni = 0; ni < 4; ++ni) {
        int pix = pix0 + wn * 64 + ni * 16 + lr;
        Cout[((size_t)(b * HID + o)) * HW + pix] = f2bf(acc[mi][ni][r] + bo);
      }
    }
  }
  __syncthreads();
  for (int e = tid; e < 1024; e += 512)
    atomicAdd(&ctx_sum[(size_t)b * 1024 + e], ctx_lds[e]);
}

// ============ GEMM2 fused with depthwise conv ============
// out_trans[b][o][pix] = sum_ch out_w[o][ch] * dw[b][ch][pix] + out_b[o]
// dw computed on the fly from xt (LDS slab: 64 ch x 4 rows x 64 cols per k-tile).
__global__ __launch_bounds__(512, 2)
void gemm2_fused_kernel(const unsigned short* __restrict__ Afrag,
                        const unsigned short* __restrict__ xt,
                        const float* __restrict__ kern, const float* __restrict__ bias,
                        unsigned short* __restrict__ Cout, float* __restrict__ bn_sums)
{
  constexpr int NT = 4;                          // KDIM 256 / 64
  __shared__ unsigned short B_sh[128 * 64];      // [pix][k] bf16, XOR-swizzled
  __shared__ unsigned short xs[64 * 260];        // [ch][4 rows][64], stride 260 (bank-spread)
  __shared__ float kf_s[72];
  __shared__ float bn_lds[512];

  const int tid  = threadIdx.x;
  const int lane = tid & 63;
  const int wv   = tid >> 6;
  const int wm   = wv >> 1, wn = wv & 1;
  const int lr   = lane & 15, lg = lane >> 4;

  const int b    = blockIdx.x >> 5;
  const int R    = blockIdx.x & 31;              // pixel tile: image rows 2R, 2R+1
  const int pix0 = R << 7;
  const int g0   = R << 1;

  if (tid < 512) bn_lds[tid] = 0.f;
  if (tid < 72)  kf_s[tid] = kern[b * 72 + tid];
  __syncthreads();

  f32x4 acc[4][4] = {};
  const int c4 = tid & 15, q = tid >> 4;
  const int prow  = q >> 4;                      // 0|1 image row within tile
  const int pcol4 = (q & 15) << 2;               // col base 0..60
  const int grp9  = (c4 >> 3) * 9;               // kf sub-index (plus 2t*9 per tile)

  const char* abase = (const char*)Afrag + wm * 8192 + lane * 16;

  bf16x8 aA[8];
  us8 rx[4];

  auto PREXS = [&](int t) {
    #pragma unroll
    for (int it = 0; it < 4; ++it) {
      int flat = it * 512 + tid;
      int ch = flat >> 5, r4 = (flat >> 3) & 3, c8 = flat & 7;
      int grow = g0 - 1 + r4;
      if ((unsigned)grow < 64u) {
        rx[it] = *(const us8*)(xt + ((size_t)(b * HID + t * 64 + ch) << 12) + grow * 64 + c8 * 8);
      } else {
        us8 z = {0, 0, 0, 0, 0, 0, 0, 0}; rx[it] = z;
      }
    }
  };
  auto WRXS = [&]() {
    #pragma unroll
    for (int it = 0; it < 4; ++it) {
      int flat = it * 512 + tid;
      int ch = flat >> 5, r4 = (flat >> 3) & 3, c8 = flat & 7;
      int o = ch * 260 + r4 * 64 + c8 * 8;
      *(us4*)(xs + o)     = *(const us4*)(&rx[it].v[0]);
      *(us4*)(xs + o + 4) = *(const us4*)(&rx[it].v[4]);
    }
  };
  auto ISSUE_A = [&](int t) {
    const char* p = abase + t * 32768;
    #pragma unroll
    for (int i = 0; i < 8; ++i) aA[i] = *(const bf16x8*)(p + i * 1024);
  };

  PREXS(0);
  ISSUE_A(0);

  for (int t = 0; t < NT; ++t) {
    WRXS();                                      // vmcnt wait inserted by compiler
    __syncthreads();
    if (t + 1 < NT) PREXS(t + 1);                // fly during dw-compute + MFMA
    // ---- depthwise 3x3 from xs -> B_sh (swizzled)
    {
      const float k0 = kf_s[2 * t * 9 + grp9 + 0], k1 = kf_s[2 * t * 9 + grp9 + 1], k2 = kf_s[2 * t * 9 + grp9 + 2];
      const float k3 = kf_s[2 * t * 9 + grp9 + 3], k4 = kf_s[2 * t * 9 + grp9 + 4], k5 = kf_s[2 * t * 9 + grp9 + 5];
      const float k6 = kf_s[2 * t * 9 + grp9 + 6], k7 = kf_s[2 * t * 9 + grp9 + 7], k8 = kf_s[2 * t * 9 + grp9 + 8];
      float dwv[4][4];
      #pragma unroll
      for (int i = 0; i < 4; ++i) {
        int ch = 4 * c4 + i;
        #pragma unroll
        for (int j = 0; j < 4; ++j) dwv[i][j] = 0.f;
        #pragma unroll
        for (int ky = 0; ky < 3; ++ky) {
          int ro = ch * 260 + (prow + ky) * 64;
          float v[6];
          unsigned int p0 = (pcol4 > 0)  ? *(const unsigned int*)(xs + ro + pcol4 - 2) : 0u;
          unsigned int p1 = *(const unsigned int*)(xs + ro + pcol4);
          unsigned int p2 = *(const unsigned int*)(xs + ro + pcol4 + 2);
          unsigned int p3 = (pcol4 < 60) ? *(const unsigned int*)(xs + ro + pcol4 + 4) : 0u;
          v[0] = bf2f((unsigned short)(p0 >> 16));
          v[1] = bf2f((unsigned short)(p1 & 0xffff));
          v[2] = bf2f((unsigned short)(p1 >> 16));
          v[3] = bf2f((unsigned short)(p2 & 0xffff));
          v[4] = bf2f((unsigned short)(p2 >> 16));
          v[5] = bf2f((unsigned short)(p3 & 0xffff));
          float ka = (ky == 0) ? k0 : (ky == 1) ? k3 : k6;
          float kb = (ky == 0) ? k1 : (ky == 1) ? k4 : k7;
          float kc = (ky == 0) ? k2 : (ky == 1) ? k5 : k8;
          #pragma unroll
          for (int j = 0; j < 4; ++j)
            dwv[i][j] += v[j] * ka + v[j + 1] * kb + v[j + 2] * kc;
        }
      }
      #pragma unroll
      for (int j = 0; j < 4; ++j) {
        int pix = 4 * q + j;
        us4 w = { f2bf(dwv[0][j]), f2bf(dwv[1][j]), f2bf(dwv[2][j]), f2bf(dwv[3][j]) };
        *(us4*)((char*)B_sh + pix * 128 + ((8 * c4) ^ ((pix & 7) << 4))) = w;
      }
    }
    __syncthreads();
    // ---- MFMA
    #pragma unroll
    for (int kk = 0; kk < 2; ++kk) {
      bf16x8 bfr[4];
      #pragma unroll
      for (int ni = 0; ni < 4; ++ni) {
        int pr = wn * 64 + ni * 16 + lr;
        bfr[ni] = *(const bf16x8*)((const char*)B_sh + pr * 128 + ((((kk << 2) | lg) ^ (pr & 7)) << 4));
      }
      #pragma unroll
      for (int mi = 0; mi < 4; ++mi)
        #pragma unroll
        for (int ni = 0; ni < 4; ++ni)
          acc[mi][ni] = __builtin_amdgcn_mfma_f32_16x16x32_bf16(aA[kk * 4 + mi], bfr[ni], acc[mi][ni], 0, 0, 0);
    }
    if (t + 1 < NT) ISSUE_A(t + 1);
  }

  // ---- epilogue: bias, bf16 store, BN partial stats
  #pragma unroll
  for (int mi = 0; mi < 4; ++mi) {
    #pragma unroll
    for (int r = 0; r < 4; ++r) {
      int o = wm * 64 + mi * 16 + lg * 4 + r;
      float bo = bias[o];
      #pragma unroll
      for (int ni = 0; ni < 4; ++ni) {
        int pix = pix0 + wn * 64 + ni * 16 + lr;
        float val = acc[mi][ni][r] + bo;
        Cout[((size_t)(b * HID + o)) * HW + pix] = f2bf(val);
        float s = val, s2 = val * val;
        #pragma unroll
        for (int msk = 1; msk < 16; msk <<= 1) {
          s  += __shfl_xor(s,  msk, 64);
          s2 += __shfl_xor(s2, msk, 64);
        }
        if (lr == 0) { atomicAdd(&bn_lds[o], s); atomicAdd(&bn_lds[256 + o], s2); }
      }
    }
  }
  __syncthreads();
  if (tid < 512) atomicAdd(&bn_sums[tid], bn_lds[tid]);
}

// wave-per-output FC layer: out[b][o] = act(scale * dot(in[b][:], w[o][:]) + bias[o])
template<int K, int N, bool RELU>
__global__ __launch_bounds__(256)
void fc_kernel(const float* __restrict__ in, const float* __restrict__ w,
               const float* __restrict__ bias, float* __restrict__ out, float scale)
{
  const int wid  = (blockIdx.x << 2) | (threadIdx.x >> 6);
  const int lane = threadIdx.x & 63;
  const int b = wid / N, o = wid - b * N;
  const float* ip = in + (size_t)b * K;
  const float* wp = w  + (size_t)o * K;
  float p = 0.f;
  #pragma unroll
  for (int k = 0; k < K / 64; ++k) p += ip[lane + k * 64] * wp[lane + k * 64];
  #pragma unroll
  for (int m = 1; m < 64; m <<= 1) p += __shfl_xor(p, m, 64);
  if (lane == 0) {
    float v = p * scale + bias[o];
    out[(size_t)b * N + o] = RELU ? fmaxf(v, 0.f) : v;
  }
}

// out = xt + scale[o]*ot + shift[o]; BN finalize folded in (per-block from bn_sums)
__global__ __launch_bounds__(256)
void final_kernel(const unsigned short* __restrict__ xt, const unsigned short* __restrict__ ot,
                  const float* __restrict__ bn_sums, const float* __restrict__ gamma,
                  const float* __restrict__ beta, float* __restrict__ out)
{
  __shared__ float sc_s[256], sh_s[256];
  {
    int t = threadIdx.x;
    const float inv_n = 1.f / 65536.f;          // B*H*W
    float m  = bn_sums[t] * inv_n;
    float v  = bn_sums[256 + t] * inv_n - m * m;
    float sc = gamma[t] * rsqrtf(v + 1e-5f);
    sc_s[t] = sc;
    sh_s[t] = beta[t] - m * sc;
  }
  __syncthreads();
  int g = blockIdx.x * 256 + threadIdx.x;       // group of 4 elements
  const int stride = 4096 * 256;
  #pragma unroll
  for (int it = 0; it < 4; ++it, g += stride) {
    int o = (g >> 10) & 255;
    us4 a = ((const us4*)xt)[g];
    us4 c = ((const us4*)ot)[g];
    float s = sc_s[o], h = sh_s[o];
    f4 r;
    #pragma unroll
    for (int j = 0; j < 4; ++j) r.v[j] = bf2f(a.v[j]) + s * bf2f(c.v[j]) + h;
    *(f4*)(out + (size_t)g * 4) = r;
  }
}

extern "C" void kernel_launch(void* const* d_in, const int* in_sizes, int n_in,
                              void* d_out, int out_size, void* d_ws, size_t ws_size,
                              hipStream_t stream)
{
  const float* x     = (const float*)d_in[0];
  const float* ctx_w = (const float*)d_in[1];
  const float* ctx_b = (const float*)d_in[2];
  const float* kg_w1 = (const float*)d_in[3];
  const float* kg_b1 = (const float*)d_in[4];
  const float* kg_w2 = (const float*)d_in[5];
  const float* kg_b2 = (const float*)d_in[6];
  const float* in_w  = (const float*)d_in[7];
  const float* in_b  = (const float*)d_in[8];
  const float* out_w = (const float*)d_in[9];
  const float* out_b = (const float*)d_in[10];
  const float* gamma = (const float*)d_in[11];
  const float* beta  = (const float*)d_in[12];
  float* out = (float*)d_out;

  char* ws = (char*)d_ws;
  unsigned short* xt = (unsigned short*)ws;                  // 32 MiB bf16 xt
  unsigned short* ot = (unsigned short*)(ws + 33554432);     // 32 MiB bf16 out_trans
  float* ctx_sum = (float*)(ws + 67108864);                  // [16][1024]
  float* bn_sums = ctx_sum + 16384;                          // [512] (zeroed by prep)
  float* kern    = bn_sums + 512;                            // [16][72]
  float* ctxbuf  = kern + 1152;                              // [16][256]
  float* hddnbuf = ctxbuf + 4096;                            // [16][512]
  unsigned short* afrag1 = (unsigned short*)(ws + 67108864 + 131072);            // 512 KiB
  unsigned short* afrag2 = (unsigned short*)(ws + 67108864 + 131072 + 524288);   // 128 KiB

  prep_kernel<<<226, 256, 0, stream>>>(in_w, afrag1, out_w, afrag2, ctx_sum);
  gemm1_kernel<<<512, 512, 0, stream>>>(afrag1, x, in_b, xt, ctx_sum);
  fc_kernel<1024, 256, true ><<<1024, 256, 0, stream>>>(ctx_sum, ctx_w, ctx_b, ctxbuf, 1.f / 4096.f);
  fc_kernel< 256, 512, true ><<<2048, 256, 0, stream>>>(ctxbuf,  kg_w1, kg_b1, hddnbuf, 1.f);
  fc_kernel< 512,  72, false><<< 288, 256, 0, stream>>>(hddnbuf, kg_w2, kg_b2, kern,    1.f);
  gemm2_fused_kernel<<<512, 512, 0, stream>>>(afrag2, xt, kern, out_b, ot, bn_sums);
  final_kernel<<<4096, 256, 0, stream>>>(xt, ot, bn_sums, gamma, beta, out);
}